// Round 9
// baseline (418.262 us; speedup 1.0000x reference)
//
#include <hip/hip_runtime.h>
#include <hip/hip_bf16.h>
#include <math.h>

typedef __attribute__((ext_vector_type(8))) short frag8;   // 8 bf16 (4 VGPRs)
typedef __attribute__((ext_vector_type(4))) float f32x4;

// ---------------- device helpers ----------------
__device__ __forceinline__ float gelu_exact(float x) {
    return 0.5f * x * (1.0f + erff(x * 0.70710678118654752f));
}
__device__ __forceinline__ float softplus_f(float x) {
    return (x > 20.0f) ? x : log1pf(expf(x));
}
__device__ __forceinline__ float sigmoid_f(float x) {
    return 1.0f / (1.0f + __expf(-x));
}
__device__ __forceinline__ unsigned short bf16bits(float x) {
    __hip_bfloat16 h = __float2bfloat16(x);
    return *(unsigned short*)&h;
}
__device__ __forceinline__ float bf2f(unsigned short u) {
    unsigned int v = ((unsigned int)u) << 16;
    return __builtin_bit_cast(float, v);
}
// sum over the 16 lanes of each DPP row-of-16 — VALU-pipe only
__device__ __forceinline__ float row_sum16(float x) {
    int t;
    t = __builtin_amdgcn_update_dpp(0, __builtin_bit_cast(int, x), 0x128, 0xf, 0xf, true); // row_ror:8
    x += __builtin_bit_cast(float, t);
    t = __builtin_amdgcn_update_dpp(0, __builtin_bit_cast(int, x), 0x124, 0xf, 0xf, true); // row_ror:4
    x += __builtin_bit_cast(float, t);
    t = __builtin_amdgcn_update_dpp(0, __builtin_bit_cast(int, x), 0x122, 0xf, 0xf, true); // row_ror:2
    x += __builtin_bit_cast(float, t);
    t = __builtin_amdgcn_update_dpp(0, __builtin_bit_cast(int, x), 0x121, 0xf, 0xf, true); // row_ror:1
    x += __builtin_bit_cast(float, t);
    return x;
}
// inclusive prefix sum over the full 64-lane wave (DPP, VALU-pipe only)
__device__ __forceinline__ float prefix_sum64(float x) {
    int t;
    t = __builtin_amdgcn_update_dpp(0, __builtin_bit_cast(int, x), 0x111, 0xf, 0xf, true); // row_shr:1
    x += __builtin_bit_cast(float, t);
    t = __builtin_amdgcn_update_dpp(0, __builtin_bit_cast(int, x), 0x112, 0xf, 0xf, true); // row_shr:2
    x += __builtin_bit_cast(float, t);
    t = __builtin_amdgcn_update_dpp(0, __builtin_bit_cast(int, x), 0x114, 0xf, 0xf, true); // row_shr:4
    x += __builtin_bit_cast(float, t);
    t = __builtin_amdgcn_update_dpp(0, __builtin_bit_cast(int, x), 0x118, 0xf, 0xf, true); // row_shr:8
    x += __builtin_bit_cast(float, t);
    t = __builtin_amdgcn_update_dpp(0, __builtin_bit_cast(int, x), 0x142, 0xa, 0xf, true); // row_bcast:15 -> rows 1,3
    x += __builtin_bit_cast(float, t);
    t = __builtin_amdgcn_update_dpp(0, __builtin_bit_cast(int, x), 0x143, 0xc, 0xf, true); // row_bcast:31 -> rows 2,3
    x += __builtin_bit_cast(float, t);
    return x;
}

// ---------------- fused fp32 -> bf16 conversion ----------------
struct CvtArgs {
    const float* src[7];
    unsigned short* dst[7];
    int n4[7];
};
__global__ __launch_bounds__(256)
void cvt_all(CvtArgs a, int total4)
{
    int i = blockIdx.x * 256 + threadIdx.x;
    if (i >= total4) return;
    int seg = 0;
    while (i >= a.n4[seg]) { i -= a.n4[seg]; seg++; }
    float4 v = reinterpret_cast<const float4*>(a.src[seg])[i];
    ushort4 o;
    o.x = bf16bits(v.x); o.y = bf16bits(v.y); o.z = bf16bits(v.z); o.w = bf16bits(v.w);
    reinterpret_cast<ushort4*>(a.dst[seg])[i] = o;
}

// ---------------- setup: Acoef = -exp(A_log) for both layers + zero l2 ----------
__global__ __launch_bounds__(256)
void setup_k(const float* __restrict__ Alog, float* __restrict__ Ac, float* l2)
{
    int i = blockIdx.x * 256 + threadIdx.x;
    if (i < 16384) Ac[i] = -__expf(Alog[i]);
    if (i == 0) *l2 = 0.0f;
}

// ---------------- generic MFMA bf16 GEMM (64x64 tile, reg-dbuf prefetch) --------
__global__ __launch_bounds__(256)
void gemm_mfma(const unsigned short* __restrict__ A,
               const unsigned short* __restrict__ W,
               const float* __restrict__ bias,
               float* __restrict__ C,
               int N, int K)
{
    __shared__ __align__(16) unsigned short As[64][40];
    __shared__ __align__(16) unsigned short Bs[64][40];

    const int tid = threadIdx.x;
    const int wid = tid >> 6, lane = tid & 63;
    const int wm = (wid >> 1) * 32, wn = (wid & 1) * 32;
    const int m0 = blockIdx.y * 64, n0 = blockIdx.x * 64;
    const int lrow = lane & 15, quad = lane >> 4;

    const int sm = tid >> 2;
    const int sk = (tid & 3) * 8;
    const int n = n0 + sm;

    f32x4 acc[2][2] = {};

    float4 av = *reinterpret_cast<const float4*>(A + (size_t)(m0 + sm) * K + sk);
    float4 bv = {0.f, 0.f, 0.f, 0.f};
    if (n < N) bv = *reinterpret_cast<const float4*>(W + (size_t)n * K + sk);

    for (int k0 = 0; k0 < K; k0 += 32) {
        *reinterpret_cast<float4*>(&As[sm][sk]) = av;
        *reinterpret_cast<float4*>(&Bs[sm][sk]) = bv;
        __syncthreads();
        if (k0 + 32 < K) {
            av = *reinterpret_cast<const float4*>(A + (size_t)(m0 + sm) * K + k0 + 32 + sk);
            if (n < N) bv = *reinterpret_cast<const float4*>(W + (size_t)n * K + k0 + 32 + sk);
        }

        frag8 a0 = *reinterpret_cast<const frag8*>(&As[wm + lrow][quad * 8]);
        frag8 a1 = *reinterpret_cast<const frag8*>(&As[wm + 16 + lrow][quad * 8]);
        frag8 b0 = *reinterpret_cast<const frag8*>(&Bs[wn + lrow][quad * 8]);
        frag8 b1 = *reinterpret_cast<const frag8*>(&Bs[wn + 16 + lrow][quad * 8]);

        acc[0][0] = __builtin_amdgcn_mfma_f32_16x16x32_bf16(a0, b0, acc[0][0], 0, 0, 0);
        acc[0][1] = __builtin_amdgcn_mfma_f32_16x16x32_bf16(a0, b1, acc[0][1], 0, 0, 0);
        acc[1][0] = __builtin_amdgcn_mfma_f32_16x16x32_bf16(a1, b0, acc[1][0], 0, 0, 0);
        acc[1][1] = __builtin_amdgcn_mfma_f32_16x16x32_bf16(a1, b1, acc[1][1], 0, 0, 0);
        __syncthreads();
    }

    #pragma unroll
    for (int mi = 0; mi < 2; mi++) {
        #pragma unroll
        for (int nj = 0; nj < 2; nj++) {
            int col = n0 + wn + nj * 16 + lrow;
            if (col >= N) continue;
            #pragma unroll
            for (int r = 0; r < 4; r++) {
                int row = m0 + wm + mi * 16 + quad * 4 + r;
                float v = acc[mi][nj][r];
                if (bias) v += bias[col];
                C[(size_t)row * N + col] = v;
            }
        }
    }
}

// ---------------- MFMA GEMM, A from ucT [B=4][K=512][T=1024] fp32 (prefetch) ----
__global__ __launch_bounds__(256)
void gemm_at(const float* __restrict__ AT,
             const unsigned short* __restrict__ W,
             float* __restrict__ C,
             int N, int K)
{
    __shared__ __align__(16) unsigned short As[64][40];
    __shared__ __align__(16) unsigned short Bs[64][40];

    const int tid = threadIdx.x;
    const int wid = tid >> 6, lane = tid & 63;
    const int wm = (wid >> 1) * 32, wn = (wid & 1) * 32;
    const int m0 = blockIdx.y * 64;
    const int bb = m0 >> 10;
    const int tb = m0 & 1023;
    const int lrow = lane & 15, quad = lane >> 4;

    const int sm = tid >> 2;
    const int sk = (tid & 3) * 8;
    const int kk0 = tid >> 4;           // 0..15
    const int mq = tid & 15;

    f32x4 acc[2][2] = {};

    float4 a0v = *reinterpret_cast<const float4*>(AT + ((size_t)(bb * 512 + kk0)) * 1024 + tb + mq * 4);
    float4 a1v = *reinterpret_cast<const float4*>(AT + ((size_t)(bb * 512 + kk0 + 16)) * 1024 + tb + mq * 4);
    float4 bv = {0.f, 0.f, 0.f, 0.f};
    if (sm < N) bv = *reinterpret_cast<const float4*>(W + (size_t)sm * K + sk);

    for (int k0 = 0; k0 < K; k0 += 32) {
        As[mq * 4 + 0][kk0]      = bf16bits(a0v.x);
        As[mq * 4 + 1][kk0]      = bf16bits(a0v.y);
        As[mq * 4 + 2][kk0]      = bf16bits(a0v.z);
        As[mq * 4 + 3][kk0]      = bf16bits(a0v.w);
        As[mq * 4 + 0][kk0 + 16] = bf16bits(a1v.x);
        As[mq * 4 + 1][kk0 + 16] = bf16bits(a1v.y);
        As[mq * 4 + 2][kk0 + 16] = bf16bits(a1v.z);
        As[mq * 4 + 3][kk0 + 16] = bf16bits(a1v.w);
        *reinterpret_cast<float4*>(&Bs[sm][sk]) = bv;
        __syncthreads();
        if (k0 + 32 < K) {
            a0v = *reinterpret_cast<const float4*>(AT + ((size_t)(bb * 512 + k0 + 32 + kk0)) * 1024 + tb + mq * 4);
            a1v = *reinterpret_cast<const float4*>(AT + ((size_t)(bb * 512 + k0 + 48 + kk0)) * 1024 + tb + mq * 4);
            if (sm < N) bv = *reinterpret_cast<const float4*>(W + (size_t)sm * K + k0 + 32 + sk);
        }

        frag8 fa0 = *reinterpret_cast<const frag8*>(&As[wm + lrow][quad * 8]);
        frag8 fa1 = *reinterpret_cast<const frag8*>(&As[wm + 16 + lrow][quad * 8]);
        frag8 fb0 = *reinterpret_cast<const frag8*>(&Bs[wn + lrow][quad * 8]);
        frag8 fb1 = *reinterpret_cast<const frag8*>(&Bs[wn + 16 + lrow][quad * 8]);

        acc[0][0] = __builtin_amdgcn_mfma_f32_16x16x32_bf16(fa0, fb0, acc[0][0], 0, 0, 0);
        acc[0][1] = __builtin_amdgcn_mfma_f32_16x16x32_bf16(fa0, fb1, acc[0][1], 0, 0, 0);
        acc[1][0] = __builtin_amdgcn_mfma_f32_16x16x32_bf16(fa1, fb0, acc[1][0], 0, 0, 0);
        acc[1][1] = __builtin_amdgcn_mfma_f32_16x16x32_bf16(fa1, fb1, acc[1][1], 0, 0, 0);
        __syncthreads();
    }

    #pragma unroll
    for (int mi = 0; mi < 2; mi++) {
        #pragma unroll
        for (int nj = 0; nj < 2; nj++) {
            int col = wn + nj * 16 + lrow;
            if (col >= N) continue;
            #pragma unroll
            for (int r = 0; r < 4; r++) {
                int row = m0 + wm + mi * 16 + quad * 4 + r;
                C[(size_t)row * N + col] = acc[mi][nj][r];
            }
        }
    }
}

// ---------------- full-row GEMM (N=256) fused LN / GELU / res / L2 (prefetch) ---
__global__ __launch_bounds__(256)
void rowgemm(const unsigned short* __restrict__ A,
             const unsigned short* __restrict__ W,
             const float* __restrict__ bias,
             const float* res,
             const float* g1, const float* b1, int gelu1,
             const float* g2, const float* b2,
             float* outF, unsigned short* outB, float* l2out, int K)
{
    __shared__ __align__(16) unsigned short As[16][40];
    __shared__ __align__(16) unsigned short Bs[256][40];
    __shared__ float red[4][16][2];
    __shared__ float sq[16];

    const int tid = threadIdx.x;
    const int w = tid >> 6, lane = tid & 63;
    const int lrow = lane & 15, quad = lane >> 4;
    const int m0 = blockIdx.x * 16;
    const int sn = tid >> 2;
    const int sk = (tid & 3) * 8;

    f32x4 acc[4] = {};

    float4 av;
    if (tid < 64) av = *reinterpret_cast<const float4*>(A + (size_t)(m0 + (tid >> 2)) * K + sk);
    float4 bv[4];
    #pragma unroll
    for (int i = 0; i < 4; i++)
        bv[i] = *reinterpret_cast<const float4*>(W + (size_t)(sn + i * 64) * K + sk);

    for (int k0 = 0; k0 < K; k0 += 32) {
        if (tid < 64) *reinterpret_cast<float4*>(&As[tid >> 2][sk]) = av;
        #pragma unroll
        for (int i = 0; i < 4; i++)
            *reinterpret_cast<float4*>(&Bs[sn + i * 64][sk]) = bv[i];
        __syncthreads();
        if (k0 + 32 < K) {
            if (tid < 64) av = *reinterpret_cast<const float4*>(A + (size_t)(m0 + (tid >> 2)) * K + k0 + 32 + sk);
            #pragma unroll
            for (int i = 0; i < 4; i++)
                bv[i] = *reinterpret_cast<const float4*>(W + (size_t)(sn + i * 64) * K + k0 + 32 + sk);
        }
        frag8 a = *reinterpret_cast<const frag8*>(&As[lrow][quad * 8]);
        #pragma unroll
        for (int nj = 0; nj < 4; nj++) {
            frag8 b = *reinterpret_cast<const frag8*>(&Bs[w * 64 + nj * 16 + lrow][quad * 8]);
            acc[nj] = __builtin_amdgcn_mfma_f32_16x16x32_bf16(a, b, acc[nj], 0, 0, 0);
        }
        __syncthreads();
    }

    float v[4][4];
    #pragma unroll
    for (int nj = 0; nj < 4; nj++) {
        int col = w * 64 + nj * 16 + lrow;
        #pragma unroll
        for (int r = 0; r < 4; r++) {
            int row = m0 + quad * 4 + r;
            float t = acc[nj][r];
            if (bias) t += bias[col];
            if (res) t += res[(size_t)row * 256 + col];
            v[nj][r] = t;
        }
    }

    if (g1) {
        #pragma unroll
        for (int r = 0; r < 4; r++) {
            float s1 = v[0][r] + v[1][r] + v[2][r] + v[3][r];
            float s2 = v[0][r]*v[0][r] + v[1][r]*v[1][r] + v[2][r]*v[2][r] + v[3][r]*v[3][r];
            s1 = row_sum16(s1); s2 = row_sum16(s2);
            if (lrow == 0) { red[w][quad * 4 + r][0] = s1; red[w][quad * 4 + r][1] = s2; }
        }
        __syncthreads();
        #pragma unroll
        for (int r = 0; r < 4; r++) {
            int rr = quad * 4 + r;
            float t1 = red[0][rr][0] + red[1][rr][0] + red[2][rr][0] + red[3][rr][0];
            float t2 = red[0][rr][1] + red[1][rr][1] + red[2][rr][1] + red[3][rr][1];
            float mu = t1 * (1.0f / 256.0f);
            float var = t2 * (1.0f / 256.0f) - mu * mu;
            float rstd = rsqrtf(var + 1e-5f);
            #pragma unroll
            for (int nj = 0; nj < 4; nj++) {
                int col = w * 64 + nj * 16 + lrow;
                float t = (v[nj][r] - mu) * rstd * g1[col] + b1[col];
                if (gelu1) t = gelu_exact(t);
                v[nj][r] = t;
            }
        }
        __syncthreads();
    } else if (gelu1) {
        #pragma unroll
        for (int nj = 0; nj < 4; nj++)
            #pragma unroll
            for (int r = 0; r < 4; r++)
                v[nj][r] = gelu_exact(v[nj][r]);
    }

    if (outF) {
        #pragma unroll
        for (int nj = 0; nj < 4; nj++) {
            int col = w * 64 + nj * 16 + lrow;
            #pragma unroll
            for (int r = 0; r < 4; r++)
                outF[(size_t)(m0 + quad * 4 + r) * 256 + col] = v[nj][r];
        }
    }

    if (l2out) {
        #pragma unroll
        for (int r = 0; r < 4; r++) {
            float s2 = v[0][r]*v[0][r] + v[1][r]*v[1][r] + v[2][r]*v[2][r] + v[3][r]*v[3][r];
            s2 = row_sum16(s2);
            if (lrow == 0) red[w][quad * 4 + r][0] = s2;
        }
        __syncthreads();
        if (tid < 16) {
            float t = red[0][tid][0] + red[1][tid][0] + red[2][tid][0] + red[3][tid][0];
            sq[tid] = sqrtf(t);
        }
        __syncthreads();
        if (tid == 0) {
            float a = 0.f;
            #pragma unroll
            for (int i = 0; i < 16; i++) a += sq[i];
            atomicAdd(l2out, a * (0.01f / 4096.0f));
        }
    }

    if (g2) {
        __syncthreads();
        #pragma unroll
        for (int r = 0; r < 4; r++) {
            float s1 = v[0][r] + v[1][r] + v[2][r] + v[3][r];
            float s2 = v[0][r]*v[0][r] + v[1][r]*v[1][r] + v[2][r]*v[2][r] + v[3][r]*v[3][r];
            s1 = row_sum16(s1); s2 = row_sum16(s2);
            if (lrow == 0) { red[w][quad * 4 + r][0] = s1; red[w][quad * 4 + r][1] = s2; }
        }
        __syncthreads();
        #pragma unroll
        for (int r = 0; r < 4; r++) {
            int rr = quad * 4 + r;
            float t1 = red[0][rr][0] + red[1][rr][0] + red[2][rr][0] + red[3][rr][0];
            float t2 = red[0][rr][1] + red[1][rr][1] + red[2][rr][1] + red[3][rr][1];
            float mu = t1 * (1.0f / 256.0f);
            float var = t2 * (1.0f / 256.0f) - mu * mu;
            float rstd = rsqrtf(var + 1e-5f);
            #pragma unroll
            for (int nj = 0; nj < 4; nj++) {
                int col = w * 64 + nj * 16 + lrow;
                outB[(size_t)(m0 + rr) * 256 + col] = bf16bits((v[nj][r] - mu) * rstd * g2[col] + b2[col]);
            }
        }
    } else if (outB) {
        #pragma unroll
        for (int nj = 0; nj < 4; nj++) {
            int col = w * 64 + nj * 16 + lrow;
            #pragma unroll
            for (int r = 0; r < 4; r++)
                outB[(size_t)(m0 + quad * 4 + r) * 256 + col] = bf16bits(v[nj][r]);
        }
    }
}

// ---------------- conv + SiLU -> ucT [b][d][t] fp32 ; silu(z) -> szT bf16 -------
__global__ __launch_bounds__(256)
void conv_silu_T(const float* __restrict__ xz, const float* __restrict__ cw,
                 const float* __restrict__ cb, float* __restrict__ ucT,
                 unsigned short* __restrict__ szT)
{
    __shared__ float xs[67][65];
    const int bx = blockIdx.x;
    const int b = bx >> 8;
    const int dt_ = (bx & 255) >> 4;
    const int tt = bx & 15;
    const int tid = threadIdx.x;
    const int t0 = tt * 64;
    const int tl = tid & 63, dgrp = tid >> 6;

    if (dt_ < 8) {
        const int d0 = dt_ * 64;
        for (int i = tid; i < 67 * 64; i += 256) {
            int rr = i >> 6, dd = i & 63;
            int tg = t0 - 3 + rr;
            xs[rr][dd] = (tg >= 0) ? xz[((size_t)(b * 1024 + tg)) * 1024 + d0 + dd] : 0.0f;
        }
        __syncthreads();
        #pragma unroll 4
        for (int dp = 0; dp < 16; dp++) {
            int dd = dp * 4 + dgrp;
            int d = d0 + dd;
            float c0 = cw[d * 4 + 0], c1 = cw[d * 4 + 1], c2 = cw[d * 4 + 2], c3 = cw[d * 4 + 3];
            float acc = cb[d] + xs[tl][dd] * c0 + xs[tl + 1][dd] * c1 + xs[tl + 2][dd] * c2 + xs[tl + 3][dd] * c3;
            ucT[((size_t)(b * 512 + d)) * 1024 + t0 + tl] = acc * sigmoid_f(acc);
        }
    } else {
        const int z0 = (dt_ - 8) * 64;
        for (int i = tid; i < 64 * 64; i += 256) {
            int rr = i >> 6, dd = i & 63;
            xs[rr][dd] = xz[((size_t)(b * 1024 + t0 + rr)) * 1024 + 512 + z0 + dd];
        }
        __syncthreads();
        #pragma unroll 4
        for (int dp = 0; dp < 16; dp++) {
            int dd = dp * 4 + dgrp;
            float v = xs[tl][dd];
            szT[((size_t)(b * 512 + z0 + dd)) * 1024 + t0 + tl] = bf16bits(v * sigmoid_f(v));
        }
    }
}

// ---------------- dt proj + softplus -> dltT ; fused B/C transpose --------------
__global__ __launch_bounds__(256)
void dtbc(const float* __restrict__ xdbc, const float* __restrict__ dtw,
          const float* __restrict__ dtb, float* __restrict__ dltT,
          float* __restrict__ BT, float* __restrict__ CT)
{
    __shared__ float xd[64][17];
    __shared__ float wS[64][16];
    __shared__ float bS[64];
    const int bx = blockIdx.x;
    const int b = bx >> 7;
    const int tt = (bx >> 3) & 15;
    const int dg = bx & 7;
    const int tid = threadIdx.x;
    const int t0 = tt * 64, d0 = dg * 64;

    for (int i = tid; i < 64 * 16; i += 256) {
        int t = i >> 4, k = i & 15;
        xd[t][k] = xdbc[((size_t)(b * 1024 + t0 + t)) * 48 + k];
    }
    for (int i = tid; i < 64 * 16; i += 256) {
        int dl = i >> 4, k = i & 15;
        wS[dl][k] = dtw[(d0 + dl) * 16 + k];
    }
    if (tid < 64) bS[tid] = dtb[d0 + tid];
    __syncthreads();

    const int tl = tid & 63, w = tid >> 6;
    #pragma unroll 4
    for (int di = 0; di < 16; di++) {
        int dl = w * 16 + di;
        float acc = bS[dl];
        #pragma unroll
        for (int k = 0; k < 16; k++) acc += xd[tl][k] * wS[dl][k];
        dltT[((size_t)(b * 512 + d0 + dl)) * 1024 + t0 + tl] = softplus_f(acc);
    }

    {
        int c = tid >> 6;
        int t = tid & 63;
        int col = dg * 4 + c;
        float v = xdbc[((size_t)(b * 1024 + t0 + t)) * 48 + 16 + col];
        if (col < 16) BT[((size_t)(b * 16 + col)) * 1024 + t0 + t] = v;
        else          CT[((size_t)(b * 16 + col - 16)) * 1024 + t0 + t] = v;
    }
}

// ---------------- chunked selective scan (1 barrier, decentralized combine) -----
__global__ __launch_bounds__(1024)
void scan_chunked(const float* __restrict__ dltT, const float* __restrict__ ucT,
                  const float* __restrict__ BT, const float* __restrict__ CT,
                  const unsigned short* __restrict__ szT,
                  const float* __restrict__ Ac,       // per-layer [512*16] = -exp(A_log)
                  const float* __restrict__ Dp,
                  unsigned short* __restrict__ y)
{
    __shared__ float aprod_s[16][64];
    __shared__ float sfin_s[16][64];
    __shared__ float sin_w[16][64];                 // per-wave, wave-synchronous
    __shared__ __align__(16) float ylocal[16][64][4]; // per-wave, wave-synchronous

    const int j = blockIdx.x;
    const int bid = (j & 7) * 64 + (j >> 3);     // XCD swizzle
    const int b = bid >> 7;
    const int d0 = (bid & 127) * 4;
    const int w = threadIdx.x >> 6;
    const int lane = threadIdx.x & 63;
    const int dsub = lane >> 4, s = lane & 15;
    const int d = d0 + dsub;

    const float Acoef = Ac[d * 16 + s];

    const float4* dp = reinterpret_cast<const float4*>(dltT + ((size_t)(b * 512 + d)) * 1024 + w * 64);
    const float4* up = reinterpret_cast<const float4*>(ucT  + ((size_t)(b * 512 + d)) * 1024 + w * 64);
    const float4* Bp = reinterpret_cast<const float4*>(BT + ((size_t)(b * 16 + s)) * 1024 + w * 64);
    const float4* Cp = reinterpret_cast<const float4*>(CT + ((size_t)(b * 16 + s)) * 1024 + w * 64);

    // ---- Phase A: local scan with cumprod (explicit q+1 prefetch) ----
    float st = 0.0f, ap = 1.0f;
    float4 dt4 = dp[0], ut4 = up[0], B4 = Bp[0], C4 = Cp[0];
    #pragma unroll
    for (int q = 0; q < 16; q++) {
        float4 ndt, nut, nB, nC;
        if (q < 15) { ndt = dp[q + 1]; nut = up[q + 1]; nB = Bp[q + 1]; nC = Cp[q + 1]; }
        const float* dtp = (const float*)&dt4;
        const float* utp = (const float*)&ut4;
        const float* Btp = (const float*)&B4;
        const float* Ctp = (const float*)&C4;
        #pragma unroll
        for (int jj = 0; jj < 4; jj++) {
            float dA = __expf(dtp[jj] * Acoef);
            st = st * dA + dtp[jj] * utp[jj] * Btp[jj];
            ap *= dA;
            float part = row_sum16(st * Ctp[jj]);
            if (s == 0) ylocal[w][q * 4 + jj][dsub] = part;
        }
        dt4 = ndt; ut4 = nut; B4 = nB; C4 = nC;
    }
    aprod_s[w][lane] = ap;
    sfin_s[w][lane] = st;
    __syncthreads();                                 // the only barrier

    // ---- decentralized combine: each wave computes its own incoming state ----
    {
        float pre = 0.0f;
        #pragma unroll
        for (int c = 0; c < 15; c++) {
            float apc = aprod_s[c][lane];
            float sfc = sfin_s[c][lane];
            float cand = sfc + apc * pre;
            pre = (c < w) ? cand : pre;
        }
        sin_w[w][lane] = pre;                        // wave-synchronous write
    }

    // ---- Phase C: lane = t; correction via prefix sums + epilogue ----
    const int t = w * 64 + lane;
    float cums[4];
    #pragma unroll
    for (int dd = 0; dd < 4; dd++)
        cums[dd] = dltT[((size_t)(b * 512 + d0 + dd)) * 1024 + t];
    #pragma unroll
    for (int dd = 0; dd < 4; dd++)
        cums[dd] = prefix_sum64(cums[dd]);

    float4 yl = *reinterpret_cast<const float4*>(&ylocal[w][lane][0]);
    float acc[4] = { yl.x, yl.y, yl.z, yl.w };

    #pragma unroll
    for (int sq = 0; sq < 4; sq++) {
        float Cs[4];
        #pragma unroll
        for (int jj = 0; jj < 4; jj++)
            Cs[jj] = CT[((size_t)(b * 16 + sq * 4 + jj)) * 1024 + t];
        #pragma unroll
        for (int dd = 0; dd < 4; dd++) {
            float4 sin4 = *reinterpret_cast<const float4*>(&sin_w[w][dd * 16 + sq * 4]);
            const float* sp = (const float*)&sin4;
            #pragma unroll
            for (int jj = 0; jj < 4; jj++) {
                float ac = Ac[(d0 + dd) * 16 + sq * 4 + jj];   // uniform -> scalar load
                acc[dd] += sp[jj] * Cs[jj] * __expf(ac * cums[dd]);
            }
        }
    }

    const size_t row = (size_t)b * 1024 + t;
    #pragma unroll
    for (int dd = 0; dd < 4; dd++) {
        float ut = ucT[((size_t)(b * 512 + d0 + dd)) * 1024 + t];
        float sz = bf2f(szT[((size_t)(b * 512 + d0 + dd)) * 1024 + t]);
        float yv = acc[dd] + ut * Dp[d0 + dd];
        y[row * 512 + d0 + dd] = bf16bits(yv * sz);
    }
}

// ---------------- launcher ----------------
extern "C" void kernel_launch(void* const* d_in, const int* in_sizes, int n_in,
                              void* d_out, int out_size, void* d_ws, size_t ws_size,
                              hipStream_t stream)
{
    const float* x      = (const float*)d_in[0];
    const float* in_b   = (const float*)d_in[2];
    const float* ln_g   = (const float*)d_in[3];
    const float* ln_b   = (const float*)d_in[4];
    const float* blk_ng  = (const float*)d_in[5];
    const float* blk_nb  = (const float*)d_in[6];
    const float* blk_cw  = (const float*)d_in[8];
    const float* blk_cb  = (const float*)d_in[9];
    const float* blk_dtw = (const float*)d_in[11];
    const float* blk_dtb = (const float*)d_in[12];
    const float* blk_Alog= (const float*)d_in[13];
    const float* blk_D   = (const float*)d_in[14];
    const float* op_b   = (const float*)d_in[17];
    const float* cls_b  = (const float*)d_in[19];
    float* out = (float*)d_out;

    const int BL = 4096;
    float* ws = (float*)d_ws;
    float* h0   = ws;                         // 1,048,576
    float* xz   = h0 + 1048576;               // 4,194,304
    float* ucT  = xz + 4194304;               // 2,097,152  [b][d][t]
    float* xdbc = ucT + 2097152;              //   196,608
    float* dltT = xdbc + 196608;              // 2,097,152  [b][d][t]
    float* BT   = dltT + 2097152;             //    65,536  [b][s][t]
    float* CT   = BT + 65536;                 //    65,536  [b][s][t]
    float* Ac   = CT + 65536;                 //    16,384
    unsigned short* szT = (unsigned short*)(Ac + 16384);  // 2,097,152 bf16
    unsigned short* wb  = szT + 2097152;      // 1,130,496
    unsigned short* hnb = wb + 1130496;       // 1,048,576
    unsigned short* ybb = hnb + 1048576;      // 2,097,152
    unsigned short* xb  = (unsigned short*)dltT;  // x bf16 (dead before dltT written)
    unsigned short* h0b = hnb;
    unsigned short* h2b = ybb;
    unsigned short* in_wb  = wb;
    unsigned short* ipw_b  = wb + 196608;
    unsigned short* xpw_b  = wb + 720896;
    unsigned short* opw_b  = wb + 770048;
    unsigned short* op_wb  = wb + 1032192;
    unsigned short* cls_wb = wb + 1097728;

    CvtArgs ca;
    ca.src[0] = x;                  ca.dst[0] = xb;     ca.n4[0] = 3145728 / 4;
    ca.src[1] = (const float*)d_in[1];  ca.dst[1] = in_wb;  ca.n4[1] = 196608 / 4;
    ca.src[2] = (const float*)d_in[7];  ca.dst[2] = ipw_b;  ca.n4[2] = 524288 / 4;
    ca.src[3] = (const float*)d_in[10]; ca.dst[3] = xpw_b;  ca.n4[3] = 49152 / 4;
    ca.src[4] = (const float*)d_in[15]; ca.dst[4] = opw_b;  ca.n4[4] = 262144 / 4;
    ca.src[5] = (const float*)d_in[16]; ca.dst[5] = op_wb;  ca.n4[5] = 65536 / 4;
    ca.src[6] = (const float*)d_in[18]; ca.dst[6] = cls_wb; ca.n4[6] = 32768 / 4;
    int total4 = (3145728 + 1130496) / 4;
    cvt_all<<<(total4 + 255) / 256, 256, 0, stream>>>(ca, total4);
    setup_k<<<64, 256, 0, stream>>>(blk_Alog, Ac, out + (size_t)BL * 128);

    // in_proj + bias + LN + GELU -> h0 (fp32), + LN(layer0) -> hnb (bf16)
    rowgemm<<<256, 256, 0, stream>>>(xb, in_wb, in_b, nullptr,
                                     ln_g, ln_b, 1,
                                     blk_ng, blk_nb,
                                     h0, hnb, nullptr, 768);

    for (int l = 0; l < 2; l++) {
        const float* cw   = blk_cw  + (size_t)l * 512 * 4;
        const float* cb   = blk_cb  + l * 512;
        const float* dtw  = blk_dtw + (size_t)l * 512 * 16;
        const float* dtb  = blk_dtb + l * 512;
        const float* Dl   = blk_D   + l * 512;
        const unsigned short* ipwl = ipw_b + (size_t)l * 262144;
        const unsigned short* xpwl = xpw_b + (size_t)l * 24576;
        const unsigned short* opwl = opw_b + (size_t)l * 131072;

        // xz = hnb @ ipw.T   (N=1024, K=256)
        gemm_mfma<<<dim3(16, 64), 256, 0, stream>>>(hnb, ipwl, nullptr, xz, 1024, 256);
        // ucT = silu(conv(u)+cb) [b][d][t]; szT = bf16(silu(z)) [b][d][t]
        conv_silu_T<<<1024, 256, 0, stream>>>(xz, cw, cb, ucT, szT);
        // xdbc = u @ xpw.T  (N=48, K=512), A read from ucT [b][k][t]
        gemm_at<<<dim3(1, 64), 256, 0, stream>>>(ucT, xpwl, xdbc, 48, 512);
        // dltT (softplus) + fused BT/CT transpose
        dtbc<<<512, 256, 0, stream>>>(xdbc, dtw, dtb, dltT, BT, CT);
        // scan -> ybb
        scan_chunked<<<512, 1024, 0, stream>>>(dltT, ucT, BT, CT, szT,
                                               Ac + (size_t)l * 8192, Dl, ybb);
        // h0 += ybb @ opw.T; layer0: +LN(layer1)->hnb; layer1: ->h0b bf16 only
        if (l == 0)
            rowgemm<<<256, 256, 0, stream>>>(ybb, opwl, nullptr, h0,
                                             nullptr, nullptr, 0,
                                             blk_ng + 256, blk_nb + 256,
                                             h0, hnb, nullptr, 512);
        else
            rowgemm<<<256, 256, 0, stream>>>(ybb, opwl, nullptr, h0,
                                             nullptr, nullptr, 0,
                                             nullptr, nullptr,
                                             nullptr, h0b, nullptr, 512);
    }

    // h2 = gelu(h0b @ op_w.T + op_b) -> h2b (bf16) + fused L2 scalar
    rowgemm<<<256, 256, 0, stream>>>(h0b, op_wb, op_b, nullptr,
                                     nullptr, nullptr, 1,
                                     nullptr, nullptr,
                                     nullptr, h2b, out + (size_t)BL * 128, 256);
    // logits = h2b @ cls_w.T + cls_b -> d_out (N=128, K=256)
    gemm_mfma<<<dim3(2, 64), 256, 0, stream>>>(h2b, cls_wb, cls_b, out, 128, 256);
}

// Round 10
// 378.090 us; speedup vs baseline: 1.1063x; 1.1063x over previous
//
#include <hip/hip_runtime.h>
#include <hip/hip_bf16.h>
#include <math.h>

typedef __attribute__((ext_vector_type(8))) short frag8;   // 8 bf16 (4 VGPRs)
typedef __attribute__((ext_vector_type(4))) float f32x4;

// ---------------- device helpers ----------------
__device__ __forceinline__ float gelu_exact(float x) {
    return 0.5f * x * (1.0f + erff(x * 0.70710678118654752f));
}
__device__ __forceinline__ float softplus_f(float x) {
    return (x > 20.0f) ? x : log1pf(expf(x));
}
__device__ __forceinline__ float sigmoid_f(float x) {
    return 1.0f / (1.0f + __expf(-x));
}
__device__ __forceinline__ unsigned short bf16bits(float x) {
    __hip_bfloat16 h = __float2bfloat16(x);
    return *(unsigned short*)&h;
}
__device__ __forceinline__ float bf2f(unsigned short u) {
    unsigned int v = ((unsigned int)u) << 16;
    return __builtin_bit_cast(float, v);
}
// sum over the 16 lanes of each DPP row-of-16 — VALU-pipe only
__device__ __forceinline__ float row_sum16(float x) {
    int t;
    t = __builtin_amdgcn_update_dpp(0, __builtin_bit_cast(int, x), 0x128, 0xf, 0xf, true); // row_ror:8
    x += __builtin_bit_cast(float, t);
    t = __builtin_amdgcn_update_dpp(0, __builtin_bit_cast(int, x), 0x124, 0xf, 0xf, true); // row_ror:4
    x += __builtin_bit_cast(float, t);
    t = __builtin_amdgcn_update_dpp(0, __builtin_bit_cast(int, x), 0x122, 0xf, 0xf, true); // row_ror:2
    x += __builtin_bit_cast(float, t);
    t = __builtin_amdgcn_update_dpp(0, __builtin_bit_cast(int, x), 0x121, 0xf, 0xf, true); // row_ror:1
    x += __builtin_bit_cast(float, t);
    return x;
}
// inclusive prefix sum over the full 64-lane wave (DPP, VALU-pipe only)
__device__ __forceinline__ float prefix_sum64(float x) {
    int t;
    t = __builtin_amdgcn_update_dpp(0, __builtin_bit_cast(int, x), 0x111, 0xf, 0xf, true); // row_shr:1
    x += __builtin_bit_cast(float, t);
    t = __builtin_amdgcn_update_dpp(0, __builtin_bit_cast(int, x), 0x112, 0xf, 0xf, true); // row_shr:2
    x += __builtin_bit_cast(float, t);
    t = __builtin_amdgcn_update_dpp(0, __builtin_bit_cast(int, x), 0x114, 0xf, 0xf, true); // row_shr:4
    x += __builtin_bit_cast(float, t);
    t = __builtin_amdgcn_update_dpp(0, __builtin_bit_cast(int, x), 0x118, 0xf, 0xf, true); // row_shr:8
    x += __builtin_bit_cast(float, t);
    t = __builtin_amdgcn_update_dpp(0, __builtin_bit_cast(int, x), 0x142, 0xa, 0xf, true); // row_bcast:15 -> rows 1,3
    x += __builtin_bit_cast(float, t);
    t = __builtin_amdgcn_update_dpp(0, __builtin_bit_cast(int, x), 0x143, 0xc, 0xf, true); // row_bcast:31 -> rows 2,3
    x += __builtin_bit_cast(float, t);
    return x;
}

// ---------------- fused fp32 -> bf16 conversion ----------------
struct CvtArgs {
    const float* src[7];
    unsigned short* dst[7];
    int n4[7];
};
__global__ __launch_bounds__(256)
void cvt_all(CvtArgs a, int total4)
{
    int i = blockIdx.x * 256 + threadIdx.x;
    if (i >= total4) return;
    int seg = 0;
    while (i >= a.n4[seg]) { i -= a.n4[seg]; seg++; }
    float4 v = reinterpret_cast<const float4*>(a.src[seg])[i];
    ushort4 o;
    o.x = bf16bits(v.x); o.y = bf16bits(v.y); o.z = bf16bits(v.z); o.w = bf16bits(v.w);
    reinterpret_cast<ushort4*>(a.dst[seg])[i] = o;
}

// ---------------- setup: Acoef = -exp(A_log) for both layers + zero l2 ----------
__global__ __launch_bounds__(256)
void setup_k(const float* __restrict__ Alog, float* __restrict__ Ac, float* l2)
{
    int i = blockIdx.x * 256 + threadIdx.x;
    if (i < 16384) Ac[i] = -__expf(Alog[i]);
    if (i == 0) *l2 = 0.0f;
}

// ---------------- generic MFMA bf16 GEMM (64x64 tile) — round-8 version --------
__global__ __launch_bounds__(256)
void gemm_mfma(const unsigned short* __restrict__ A,
               const unsigned short* __restrict__ W,
               const float* __restrict__ bias,
               float* __restrict__ C,
               int N, int K)
{
    __shared__ __align__(16) unsigned short As[64][40];
    __shared__ __align__(16) unsigned short Bs[64][40];

    const int tid = threadIdx.x;
    const int wid = tid >> 6, lane = tid & 63;
    const int wm = (wid >> 1) * 32, wn = (wid & 1) * 32;
    const int m0 = blockIdx.y * 64, n0 = blockIdx.x * 64;
    const int lrow = lane & 15, quad = lane >> 4;

    const int sm = tid >> 2;
    const int sk = (tid & 3) * 8;

    f32x4 acc[2][2] = {};

    for (int k0 = 0; k0 < K; k0 += 32) {
        float4 av = *reinterpret_cast<const float4*>(A + (size_t)(m0 + sm) * K + k0 + sk);
        *reinterpret_cast<float4*>(&As[sm][sk]) = av;
        float4 bv = {0.f, 0.f, 0.f, 0.f};
        int n = n0 + sm;
        if (n < N) bv = *reinterpret_cast<const float4*>(W + (size_t)n * K + k0 + sk);
        *reinterpret_cast<float4*>(&Bs[sm][sk]) = bv;
        __syncthreads();

        frag8 a0 = *reinterpret_cast<const frag8*>(&As[wm + lrow][quad * 8]);
        frag8 a1 = *reinterpret_cast<const frag8*>(&As[wm + 16 + lrow][quad * 8]);
        frag8 b0 = *reinterpret_cast<const frag8*>(&Bs[wn + lrow][quad * 8]);
        frag8 b1 = *reinterpret_cast<const frag8*>(&Bs[wn + 16 + lrow][quad * 8]);

        acc[0][0] = __builtin_amdgcn_mfma_f32_16x16x32_bf16(a0, b0, acc[0][0], 0, 0, 0);
        acc[0][1] = __builtin_amdgcn_mfma_f32_16x16x32_bf16(a0, b1, acc[0][1], 0, 0, 0);
        acc[1][0] = __builtin_amdgcn_mfma_f32_16x16x32_bf16(a1, b0, acc[1][0], 0, 0, 0);
        acc[1][1] = __builtin_amdgcn_mfma_f32_16x16x32_bf16(a1, b1, acc[1][1], 0, 0, 0);
        __syncthreads();
    }

    #pragma unroll
    for (int mi = 0; mi < 2; mi++) {
        #pragma unroll
        for (int nj = 0; nj < 2; nj++) {
            int col = n0 + wn + nj * 16 + lrow;
            if (col >= N) continue;
            #pragma unroll
            for (int r = 0; r < 4; r++) {
                int row = m0 + wm + mi * 16 + quad * 4 + r;
                float v = acc[mi][nj][r];
                if (bias) v += bias[col];
                C[(size_t)row * N + col] = v;
            }
        }
    }
}

// ---------------- MFMA GEMM, A from ucT [B=4][K=512][T=1024] fp32 — round-8 ----
__global__ __launch_bounds__(256)
void gemm_at(const float* __restrict__ AT,
             const unsigned short* __restrict__ W,
             float* __restrict__ C,
             int N, int K)
{
    __shared__ __align__(16) unsigned short As[64][40];
    __shared__ __align__(16) unsigned short Bs[64][40];

    const int tid = threadIdx.x;
    const int wid = tid >> 6, lane = tid & 63;
    const int wm = (wid >> 1) * 32, wn = (wid & 1) * 32;
    const int m0 = blockIdx.y * 64;
    const int bb = m0 >> 10;          // batch of this m-tile
    const int tb = m0 & 1023;         // t-base of this m-tile
    const int lrow = lane & 15, quad = lane >> 4;

    const int sm = tid >> 2;
    const int sk = (tid & 3) * 8;

    f32x4 acc[2][2] = {};

    for (int k0 = 0; k0 < K; k0 += 32) {
        #pragma unroll
        for (int p = 0; p < 2; p++) {
            int kk = (tid >> 4) + p * 16;          // 0..31
            int mq = tid & 15;                     // float4 index along m
            float4 v = *reinterpret_cast<const float4*>(AT + ((size_t)(bb * 512 + k0 + kk)) * 1024 + tb + mq * 4);
            As[mq * 4 + 0][kk] = bf16bits(v.x);
            As[mq * 4 + 1][kk] = bf16bits(v.y);
            As[mq * 4 + 2][kk] = bf16bits(v.z);
            As[mq * 4 + 3][kk] = bf16bits(v.w);
        }
        float4 bv = {0.f, 0.f, 0.f, 0.f};
        if (sm < N) bv = *reinterpret_cast<const float4*>(W + (size_t)sm * K + k0 + sk);
        *reinterpret_cast<float4*>(&Bs[sm][sk]) = bv;
        __syncthreads();

        frag8 a0 = *reinterpret_cast<const frag8*>(&As[wm + lrow][quad * 8]);
        frag8 a1 = *reinterpret_cast<const frag8*>(&As[wm + 16 + lrow][quad * 8]);
        frag8 b0 = *reinterpret_cast<const frag8*>(&Bs[wn + lrow][quad * 8]);
        frag8 b1 = *reinterpret_cast<const frag8*>(&Bs[wn + 16 + lrow][quad * 8]);

        acc[0][0] = __builtin_amdgcn_mfma_f32_16x16x32_bf16(a0, b0, acc[0][0], 0, 0, 0);
        acc[0][1] = __builtin_amdgcn_mfma_f32_16x16x32_bf16(a0, b1, acc[0][1], 0, 0, 0);
        acc[1][0] = __builtin_amdgcn_mfma_f32_16x16x32_bf16(a1, b0, acc[1][0], 0, 0, 0);
        acc[1][1] = __builtin_amdgcn_mfma_f32_16x16x32_bf16(a1, b1, acc[1][1], 0, 0, 0);
        __syncthreads();
    }

    #pragma unroll
    for (int mi = 0; mi < 2; mi++) {
        #pragma unroll
        for (int nj = 0; nj < 2; nj++) {
            int col = wn + nj * 16 + lrow;
            if (col >= N) continue;
            #pragma unroll
            for (int r = 0; r < 4; r++) {
                int row = m0 + wm + mi * 16 + quad * 4 + r;
                C[(size_t)row * N + col] = acc[mi][nj][r];
            }
        }
    }
}

// ---------------- full-row GEMM (N=256) fused LN / GELU / res / L2 — round-8 ---
__global__ __launch_bounds__(256)
void rowgemm(const unsigned short* __restrict__ A,
             const unsigned short* __restrict__ W,
             const float* __restrict__ bias,
             const float* res,
             const float* g1, const float* b1, int gelu1,
             const float* g2, const float* b2,
             float* outF, unsigned short* outB, float* l2out, int K)
{
    __shared__ __align__(16) unsigned short As[16][40];
    __shared__ __align__(16) unsigned short Bs[256][40];
    __shared__ float red[4][16][2];
    __shared__ float sq[16];

    const int tid = threadIdx.x;
    const int w = tid >> 6, lane = tid & 63;
    const int lrow = lane & 15, quad = lane >> 4;
    const int m0 = blockIdx.x * 16;

    f32x4 acc[4] = {};

    for (int k0 = 0; k0 < K; k0 += 32) {
        if (tid < 64) {
            float4 av = *reinterpret_cast<const float4*>(A + (size_t)(m0 + (tid >> 2)) * K + k0 + (tid & 3) * 8);
            *reinterpret_cast<float4*>(&As[tid >> 2][(tid & 3) * 8]) = av;
        }
        #pragma unroll
        for (int i = 0; i < 4; i++) {
            int n = (tid >> 2) + i * 64;
            float4 bv = *reinterpret_cast<const float4*>(W + (size_t)n * K + k0 + (tid & 3) * 8);
            *reinterpret_cast<float4*>(&Bs[n][(tid & 3) * 8]) = bv;
        }
        __syncthreads();
        frag8 a = *reinterpret_cast<const frag8*>(&As[lrow][quad * 8]);
        #pragma unroll
        for (int nj = 0; nj < 4; nj++) {
            frag8 b = *reinterpret_cast<const frag8*>(&Bs[w * 64 + nj * 16 + lrow][quad * 8]);
            acc[nj] = __builtin_amdgcn_mfma_f32_16x16x32_bf16(a, b, acc[nj], 0, 0, 0);
        }
        __syncthreads();
    }

    float v[4][4];
    #pragma unroll
    for (int nj = 0; nj < 4; nj++) {
        int col = w * 64 + nj * 16 + lrow;
        #pragma unroll
        for (int r = 0; r < 4; r++) {
            int row = m0 + quad * 4 + r;
            float t = acc[nj][r];
            if (bias) t += bias[col];
            if (res) t += res[(size_t)row * 256 + col];
            v[nj][r] = t;
        }
    }

    if (g1) {
        #pragma unroll
        for (int r = 0; r < 4; r++) {
            float s1 = v[0][r] + v[1][r] + v[2][r] + v[3][r];
            float s2 = v[0][r]*v[0][r] + v[1][r]*v[1][r] + v[2][r]*v[2][r] + v[3][r]*v[3][r];
            s1 = row_sum16(s1); s2 = row_sum16(s2);
            if (lrow == 0) { red[w][quad * 4 + r][0] = s1; red[w][quad * 4 + r][1] = s2; }
        }
        __syncthreads();
        #pragma unroll
        for (int r = 0; r < 4; r++) {
            int rr = quad * 4 + r;
            float t1 = red[0][rr][0] + red[1][rr][0] + red[2][rr][0] + red[3][rr][0];
            float t2 = red[0][rr][1] + red[1][rr][1] + red[2][rr][1] + red[3][rr][1];
            float mu = t1 * (1.0f / 256.0f);
            float var = t2 * (1.0f / 256.0f) - mu * mu;
            float rstd = rsqrtf(var + 1e-5f);
            #pragma unroll
            for (int nj = 0; nj < 4; nj++) {
                int col = w * 64 + nj * 16 + lrow;
                float t = (v[nj][r] - mu) * rstd * g1[col] + b1[col];
                if (gelu1) t = gelu_exact(t);
                v[nj][r] = t;
            }
        }
        __syncthreads();
    } else if (gelu1) {
        #pragma unroll
        for (int nj = 0; nj < 4; nj++)
            #pragma unroll
            for (int r = 0; r < 4; r++)
                v[nj][r] = gelu_exact(v[nj][r]);
    }

    if (outF) {
        #pragma unroll
        for (int nj = 0; nj < 4; nj++) {
            int col = w * 64 + nj * 16 + lrow;
            #pragma unroll
            for (int r = 0; r < 4; r++)
                outF[(size_t)(m0 + quad * 4 + r) * 256 + col] = v[nj][r];
        }
    }

    if (l2out) {
        #pragma unroll
        for (int r = 0; r < 4; r++) {
            float s2 = v[0][r]*v[0][r] + v[1][r]*v[1][r] + v[2][r]*v[2][r] + v[3][r]*v[3][r];
            s2 = row_sum16(s2);
            if (lrow == 0) red[w][quad * 4 + r][0] = s2;
        }
        __syncthreads();
        if (tid < 16) {
            float t = red[0][tid][0] + red[1][tid][0] + red[2][tid][0] + red[3][tid][0];
            sq[tid] = sqrtf(t);
        }
        __syncthreads();
        if (tid == 0) {
            float a = 0.f;
            #pragma unroll
            for (int i = 0; i < 16; i++) a += sq[i];
            atomicAdd(l2out, a * (0.01f / 4096.0f));
        }
    }

    if (g2) {
        __syncthreads();
        #pragma unroll
        for (int r = 0; r < 4; r++) {
            float s1 = v[0][r] + v[1][r] + v[2][r] + v[3][r];
            float s2 = v[0][r]*v[0][r] + v[1][r]*v[1][r] + v[2][r]*v[2][r] + v[3][r]*v[3][r];
            s1 = row_sum16(s1); s2 = row_sum16(s2);
            if (lrow == 0) { red[w][quad * 4 + r][0] = s1; red[w][quad * 4 + r][1] = s2; }
        }
        __syncthreads();
        #pragma unroll
        for (int r = 0; r < 4; r++) {
            int rr = quad * 4 + r;
            float t1 = red[0][rr][0] + red[1][rr][0] + red[2][rr][0] + red[3][rr][0];
            float t2 = red[0][rr][1] + red[1][rr][1] + red[2][rr][1] + red[3][rr][1];
            float mu = t1 * (1.0f / 256.0f);
            float var = t2 * (1.0f / 256.0f) - mu * mu;
            float rstd = rsqrtf(var + 1e-5f);
            #pragma unroll
            for (int nj = 0; nj < 4; nj++) {
                int col = w * 64 + nj * 16 + lrow;
                outB[(size_t)(m0 + rr) * 256 + col] = bf16bits((v[nj][r] - mu) * rstd * g2[col] + b2[col]);
            }
        }
    } else if (outB) {
        #pragma unroll
        for (int nj = 0; nj < 4; nj++) {
            int col = w * 64 + nj * 16 + lrow;
            #pragma unroll
            for (int r = 0; r < 4; r++)
                outB[(size_t)(m0 + quad * 4 + r) * 256 + col] = bf16bits(v[nj][r]);
        }
    }
}

// ---------------- conv + SiLU -> ucT [b][d][t] fp32 ; silu(z) -> szT bf16 -------
__global__ __launch_bounds__(256)
void conv_silu_T(const float* __restrict__ xz, const float* __restrict__ cw,
                 const float* __restrict__ cb, float* __restrict__ ucT,
                 unsigned short* __restrict__ szT)
{
    __shared__ float xs[67][65];
    const int bx = blockIdx.x;
    const int b = bx >> 8;
    const int dt_ = (bx & 255) >> 4;
    const int tt = bx & 15;
    const int tid = threadIdx.x;
    const int t0 = tt * 64;
    const int tl = tid & 63, dgrp = tid >> 6;

    if (dt_ < 8) {
        const int d0 = dt_ * 64;
        for (int i = tid; i < 67 * 64; i += 256) {
            int rr = i >> 6, dd = i & 63;
            int tg = t0 - 3 + rr;
            xs[rr][dd] = (tg >= 0) ? xz[((size_t)(b * 1024 + tg)) * 1024 + d0 + dd] : 0.0f;
        }
        __syncthreads();
        #pragma unroll 4
        for (int dp = 0; dp < 16; dp++) {
            int dd = dp * 4 + dgrp;
            int d = d0 + dd;
            float c0 = cw[d * 4 + 0], c1 = cw[d * 4 + 1], c2 = cw[d * 4 + 2], c3 = cw[d * 4 + 3];
            float acc = cb[d] + xs[tl][dd] * c0 + xs[tl + 1][dd] * c1 + xs[tl + 2][dd] * c2 + xs[tl + 3][dd] * c3;
            ucT[((size_t)(b * 512 + d)) * 1024 + t0 + tl] = acc * sigmoid_f(acc);
        }
    } else {
        const int z0 = (dt_ - 8) * 64;
        for (int i = tid; i < 64 * 64; i += 256) {
            int rr = i >> 6, dd = i & 63;
            xs[rr][dd] = xz[((size_t)(b * 1024 + t0 + rr)) * 1024 + 512 + z0 + dd];
        }
        __syncthreads();
        #pragma unroll 4
        for (int dp = 0; dp < 16; dp++) {
            int dd = dp * 4 + dgrp;
            float v = xs[tl][dd];
            szT[((size_t)(b * 512 + z0 + dd)) * 1024 + t0 + tl] = bf16bits(v * sigmoid_f(v));
        }
    }
}

// ---------------- dt proj + softplus -> dltT ; fused B/C transpose --------------
__global__ __launch_bounds__(256)
void dtbc(const float* __restrict__ xdbc, const float* __restrict__ dtw,
          const float* __restrict__ dtb, float* __restrict__ dltT,
          float* __restrict__ BT, float* __restrict__ CT)
{
    __shared__ float xd[64][17];
    __shared__ float wS[64][16];
    __shared__ float bS[64];
    const int bx = blockIdx.x;
    const int b = bx >> 7;
    const int tt = (bx >> 3) & 15;
    const int dg = bx & 7;
    const int tid = threadIdx.x;
    const int t0 = tt * 64, d0 = dg * 64;

    for (int i = tid; i < 64 * 16; i += 256) {
        int t = i >> 4, k = i & 15;
        xd[t][k] = xdbc[((size_t)(b * 1024 + t0 + t)) * 48 + k];
    }
    for (int i = tid; i < 64 * 16; i += 256) {
        int dl = i >> 4, k = i & 15;
        wS[dl][k] = dtw[(d0 + dl) * 16 + k];
    }
    if (tid < 64) bS[tid] = dtb[d0 + tid];
    __syncthreads();

    const int tl = tid & 63, w = tid >> 6;
    #pragma unroll 4
    for (int di = 0; di < 16; di++) {
        int dl = w * 16 + di;
        float acc = bS[dl];
        #pragma unroll
        for (int k = 0; k < 16; k++) acc += xd[tl][k] * wS[dl][k];
        dltT[((size_t)(b * 512 + d0 + dl)) * 1024 + t0 + tl] = softplus_f(acc);
    }

    {
        int c = tid >> 6;
        int t = tid & 63;
        int col = dg * 4 + c;
        float v = xdbc[((size_t)(b * 1024 + t0 + t)) * 48 + 16 + col];
        if (col < 16) BT[((size_t)(b * 16 + col)) * 1024 + t0 + t] = v;
        else          CT[((size_t)(b * 16 + col - 16)) * 1024 + t0 + t] = v;
    }
}

// ---------------- chunked selective scan (1 barrier, decentralized combine) -----
__global__ __launch_bounds__(1024)
void scan_chunked(const float* __restrict__ dltT, const float* __restrict__ ucT,
                  const float* __restrict__ BT, const float* __restrict__ CT,
                  const unsigned short* __restrict__ szT,
                  const float* __restrict__ Ac,       // per-layer [512*16] = -exp(A_log)
                  const float* __restrict__ Dp,
                  unsigned short* __restrict__ y)
{
    __shared__ float aprod_s[16][64];
    __shared__ float sfin_s[16][64];
    __shared__ float sin_w[16][64];                 // per-wave, wave-synchronous
    __shared__ __align__(16) float ylocal[16][64][4]; // per-wave, wave-synchronous

    const int j = blockIdx.x;
    const int bid = (j & 7) * 64 + (j >> 3);     // XCD swizzle
    const int b = bid >> 7;
    const int d0 = (bid & 127) * 4;
    const int w = threadIdx.x >> 6;
    const int lane = threadIdx.x & 63;
    const int dsub = lane >> 4, s = lane & 15;
    const int d = d0 + dsub;

    const float Acoef = Ac[d * 16 + s];

    const float4* dp = reinterpret_cast<const float4*>(dltT + ((size_t)(b * 512 + d)) * 1024 + w * 64);
    const float4* up = reinterpret_cast<const float4*>(ucT  + ((size_t)(b * 512 + d)) * 1024 + w * 64);
    const float4* Bp = reinterpret_cast<const float4*>(BT + ((size_t)(b * 16 + s)) * 1024 + w * 64);
    const float4* Cp = reinterpret_cast<const float4*>(CT + ((size_t)(b * 16 + s)) * 1024 + w * 64);

    // ---- Phase A: local scan with cumprod (explicit q+1 prefetch) ----
    float st = 0.0f, ap = 1.0f;
    float4 dt4 = dp[0], ut4 = up[0], B4 = Bp[0], C4 = Cp[0];
    #pragma unroll
    for (int q = 0; q < 16; q++) {
        float4 ndt, nut, nB, nC;
        if (q < 15) { ndt = dp[q + 1]; nut = up[q + 1]; nB = Bp[q + 1]; nC = Cp[q + 1]; }
        const float* dtp = (const float*)&dt4;
        const float* utp = (const float*)&ut4;
        const float* Btp = (const float*)&B4;
        const float* Ctp = (const float*)&C4;
        #pragma unroll
        for (int jj = 0; jj < 4; jj++) {
            float dA = __expf(dtp[jj] * Acoef);
            st = st * dA + dtp[jj] * utp[jj] * Btp[jj];
            ap *= dA;
            float part = row_sum16(st * Ctp[jj]);
            if (s == 0) ylocal[w][q * 4 + jj][dsub] = part;
        }
        dt4 = ndt; ut4 = nut; B4 = nB; C4 = nC;
    }
    aprod_s[w][lane] = ap;
    sfin_s[w][lane] = st;
    __syncthreads();                                 // the only barrier

    // ---- decentralized combine: each wave computes its own incoming state ----
    {
        float pre = 0.0f;
        #pragma unroll
        for (int c = 0; c < 15; c++) {
            float apc = aprod_s[c][lane];
            float sfc = sfin_s[c][lane];
            float cand = sfc + apc * pre;
            pre = (c < w) ? cand : pre;
        }
        sin_w[w][lane] = pre;                        // wave-synchronous write
    }

    // ---- Phase C: lane = t; correction via prefix sums + epilogue ----
    const int t = w * 64 + lane;
    float cums[4];
    #pragma unroll
    for (int dd = 0; dd < 4; dd++)
        cums[dd] = dltT[((size_t)(b * 512 + d0 + dd)) * 1024 + t];
    #pragma unroll
    for (int dd = 0; dd < 4; dd++)
        cums[dd] = prefix_sum64(cums[dd]);

    float4 yl = *reinterpret_cast<const float4*>(&ylocal[w][lane][0]);
    float acc[4] = { yl.x, yl.y, yl.z, yl.w };

    #pragma unroll
    for (int sq = 0; sq < 4; sq++) {
        float Cs[4];
        #pragma unroll
        for (int jj = 0; jj < 4; jj++)
            Cs[jj] = CT[((size_t)(b * 16 + sq * 4 + jj)) * 1024 + t];
        #pragma unroll
        for (int dd = 0; dd < 4; dd++) {
            float4 sin4 = *reinterpret_cast<const float4*>(&sin_w[w][dd * 16 + sq * 4]);
            const float* sp = (const float*)&sin4;
            #pragma unroll
            for (int jj = 0; jj < 4; jj++) {
                float ac = Ac[(d0 + dd) * 16 + sq * 4 + jj];   // uniform -> scalar load
                acc[dd] += sp[jj] * Cs[jj] * __expf(ac * cums[dd]);
            }
        }
    }

    const size_t row = (size_t)b * 1024 + t;
    #pragma unroll
    for (int dd = 0; dd < 4; dd++) {
        float ut = ucT[((size_t)(b * 512 + d0 + dd)) * 1024 + t];
        float sz = bf2f(szT[((size_t)(b * 512 + d0 + dd)) * 1024 + t]);
        float yv = acc[dd] + ut * Dp[d0 + dd];
        y[row * 512 + d0 + dd] = bf16bits(yv * sz);
    }
}

// ---------------- launcher ----------------
extern "C" void kernel_launch(void* const* d_in, const int* in_sizes, int n_in,
                              void* d_out, int out_size, void* d_ws, size_t ws_size,
                              hipStream_t stream)
{
    const float* x      = (const float*)d_in[0];
    const float* in_b   = (const float*)d_in[2];
    const float* ln_g   = (const float*)d_in[3];
    const float* ln_b   = (const float*)d_in[4];
    const float* blk_ng  = (const float*)d_in[5];
    const float* blk_nb  = (const float*)d_in[6];
    const float* blk_cw  = (const float*)d_in[8];
    const float* blk_cb  = (const float*)d_in[9];
    const float* blk_dtw = (const float*)d_in[11];
    const float* blk_dtb = (const float*)d_in[12];
    const float* blk_Alog= (const float*)d_in[13];
    const float* blk_D   = (const float*)d_in[14];
    const float* op_b   = (const float*)d_in[17];
    const float* cls_b  = (const float*)d_in[19];
    float* out = (float*)d_out;

    const int BL = 4096;
    float* ws = (float*)d_ws;
    float* h0   = ws;                         // 1,048,576
    float* xz   = h0 + 1048576;               // 4,194,304
    float* ucT  = xz + 4194304;               // 2,097,152  [b][d][t]
    float* xdbc = ucT + 2097152;              //   196,608
    float* dltT = xdbc + 196608;              // 2,097,152  [b][d][t]
    float* BT   = dltT + 2097152;             //    65,536  [b][s][t]
    float* CT   = BT + 65536;                 //    65,536  [b][s][t]
    float* Ac   = CT + 65536;                 //    16,384
    unsigned short* szT = (unsigned short*)(Ac + 16384);  // 2,097,152 bf16
    unsigned short* wb  = szT + 2097152;      // 1,130,496
    unsigned short* hnb = wb + 1130496;       // 1,048,576
    unsigned short* ybb = hnb + 1048576;      // 2,097,152
    unsigned short* xb  = (unsigned short*)dltT;  // x bf16 (dead before dltT written)
    unsigned short* h0b = hnb;
    unsigned short* h2b = ybb;
    unsigned short* in_wb  = wb;
    unsigned short* ipw_b  = wb + 196608;
    unsigned short* xpw_b  = wb + 720896;
    unsigned short* opw_b  = wb + 770048;
    unsigned short* op_wb  = wb + 1032192;
    unsigned short* cls_wb = wb + 1097728;

    CvtArgs ca;
    ca.src[0] = x;                  ca.dst[0] = xb;     ca.n4[0] = 3145728 / 4;
    ca.src[1] = (const float*)d_in[1];  ca.dst[1] = in_wb;  ca.n4[1] = 196608 / 4;
    ca.src[2] = (const float*)d_in[7];  ca.dst[2] = ipw_b;  ca.n4[2] = 524288 / 4;
    ca.src[3] = (const float*)d_in[10]; ca.dst[3] = xpw_b;  ca.n4[3] = 49152 / 4;
    ca.src[4] = (const float*)d_in[15]; ca.dst[4] = opw_b;  ca.n4[4] = 262144 / 4;
    ca.src[5] = (const float*)d_in[16]; ca.dst[5] = op_wb;  ca.n4[5] = 65536 / 4;
    ca.src[6] = (const float*)d_in[18]; ca.dst[6] = cls_wb; ca.n4[6] = 32768 / 4;
    int total4 = (3145728 + 1130496) / 4;
    cvt_all<<<(total4 + 255) / 256, 256, 0, stream>>>(ca, total4);
    setup_k<<<64, 256, 0, stream>>>(blk_Alog, Ac, out + (size_t)BL * 128);

    // in_proj + bias + LN + GELU -> h0 (fp32), + LN(layer0) -> hnb (bf16)
    rowgemm<<<256, 256, 0, stream>>>(xb, in_wb, in_b, nullptr,
                                     ln_g, ln_b, 1,
                                     blk_ng, blk_nb,
                                     h0, hnb, nullptr, 768);

    for (int l = 0; l < 2; l++) {
        const float* cw   = blk_cw  + (size_t)l * 512 * 4;
        const float* cb   = blk_cb  + l * 512;
        const float* dtw  = blk_dtw + (size_t)l * 512 * 16;
        const float* dtb  = blk_dtb + l * 512;
        const float* Dl   = blk_D   + l * 512;
        const unsigned short* ipwl = ipw_b + (size_t)l * 262144;
        const unsigned short* xpwl = xpw_b + (size_t)l * 24576;
        const unsigned short* opwl = opw_b + (size_t)l * 131072;

        // xz = hnb @ ipw.T   (N=1024, K=256)
        gemm_mfma<<<dim3(16, 64), 256, 0, stream>>>(hnb, ipwl, nullptr, xz, 1024, 256);
        // ucT = silu(conv(u)+cb) [b][d][t]; szT = bf16(silu(z)) [b][d][t]
        conv_silu_T<<<1024, 256, 0, stream>>>(xz, cw, cb, ucT, szT);
        // xdbc = u @ xpw.T  (N=48, K=512), A read from ucT [b][k][t]
        gemm_at<<<dim3(1, 64), 256, 0, stream>>>(ucT, xpwl, xdbc, 48, 512);
        // dltT (softplus) + fused BT/CT transpose
        dtbc<<<512, 256, 0, stream>>>(xdbc, dtw, dtb, dltT, BT, CT);
        // scan -> ybb
        scan_chunked<<<512, 1024, 0, stream>>>(dltT, ucT, BT, CT, szT,
                                               Ac + (size_t)l * 8192, Dl, ybb);
        // h0 += ybb @ opw.T; layer0: +LN(layer1)->hnb; layer1: ->h0b bf16 only
        if (l == 0)
            rowgemm<<<256, 256, 0, stream>>>(ybb, opwl, nullptr, h0,
                                             nullptr, nullptr, 0,
                                             blk_ng + 256, blk_nb + 256,
                                             h0, hnb, nullptr, 512);
        else
            rowgemm<<<256, 256, 0, stream>>>(ybb, opwl, nullptr, h0,
                                             nullptr, nullptr, 0,
                                             nullptr, nullptr,
                                             nullptr, h0b, nullptr, 512);
    }

    // h2 = gelu(h0b @ op_w.T + op_b) -> h2b (bf16) + fused L2 scalar
    rowgemm<<<256, 256, 0, stream>>>(h0b, op_wb, op_b, nullptr,
                                     nullptr, nullptr, 1,
                                     nullptr, nullptr,
                                     nullptr, h2b, out + (size_t)BL * 128, 256);
    // logits = h2b @ cls_w.T + cls_b -> d_out (N=128, K=256)
    gemm_mfma<<<dim3(2, 64), 256, 0, stream>>>(h2b, cls_wb, cls_b, out, 128, 256);
}

// Round 11
// 361.292 us; speedup vs baseline: 1.1577x; 1.0465x over previous
//
#include <hip/hip_runtime.h>
#include <hip/hip_bf16.h>
#include <math.h>

typedef __attribute__((ext_vector_type(8))) short frag8;   // 8 bf16 (4 VGPRs)
typedef __attribute__((ext_vector_type(4))) float f32x4;

// ---------------- device helpers ----------------
__device__ __forceinline__ float gelu_exact(float x) {
    return 0.5f * x * (1.0f + erff(x * 0.70710678118654752f));
}
__device__ __forceinline__ float softplus_f(float x) {
    return (x > 20.0f) ? x : log1pf(expf(x));
}
__device__ __forceinline__ float sigmoid_f(float x) {
    return 1.0f / (1.0f + __expf(-x));
}
__device__ __forceinline__ unsigned short bf16bits(float x) {
    __hip_bfloat16 h = __float2bfloat16(x);
    return *(unsigned short*)&h;
}
__device__ __forceinline__ float bf2f(unsigned short u) {
    unsigned int v = ((unsigned int)u) << 16;
    return __builtin_bit_cast(float, v);
}
// sum over the 16 lanes of each DPP row-of-16 — VALU-pipe only
__device__ __forceinline__ float row_sum16(float x) {
    int t;
    t = __builtin_amdgcn_update_dpp(0, __builtin_bit_cast(int, x), 0x128, 0xf, 0xf, true); // row_ror:8
    x += __builtin_bit_cast(float, t);
    t = __builtin_amdgcn_update_dpp(0, __builtin_bit_cast(int, x), 0x124, 0xf, 0xf, true); // row_ror:4
    x += __builtin_bit_cast(float, t);
    t = __builtin_amdgcn_update_dpp(0, __builtin_bit_cast(int, x), 0x122, 0xf, 0xf, true); // row_ror:2
    x += __builtin_bit_cast(float, t);
    t = __builtin_amdgcn_update_dpp(0, __builtin_bit_cast(int, x), 0x121, 0xf, 0xf, true); // row_ror:1
    x += __builtin_bit_cast(float, t);
    return x;
}
// inclusive prefix sum over the full 64-lane wave (DPP, VALU-pipe only)
__device__ __forceinline__ float prefix_sum64(float x) {
    int t;
    t = __builtin_amdgcn_update_dpp(0, __builtin_bit_cast(int, x), 0x111, 0xf, 0xf, true); // row_shr:1
    x += __builtin_bit_cast(float, t);
    t = __builtin_amdgcn_update_dpp(0, __builtin_bit_cast(int, x), 0x112, 0xf, 0xf, true); // row_shr:2
    x += __builtin_bit_cast(float, t);
    t = __builtin_amdgcn_update_dpp(0, __builtin_bit_cast(int, x), 0x114, 0xf, 0xf, true); // row_shr:4
    x += __builtin_bit_cast(float, t);
    t = __builtin_amdgcn_update_dpp(0, __builtin_bit_cast(int, x), 0x118, 0xf, 0xf, true); // row_shr:8
    x += __builtin_bit_cast(float, t);
    t = __builtin_amdgcn_update_dpp(0, __builtin_bit_cast(int, x), 0x142, 0xa, 0xf, true); // row_bcast:15 -> rows 1,3
    x += __builtin_bit_cast(float, t);
    t = __builtin_amdgcn_update_dpp(0, __builtin_bit_cast(int, x), 0x143, 0xc, 0xf, true); // row_bcast:31 -> rows 2,3
    x += __builtin_bit_cast(float, t);
    return x;
}

// ---------------- fused fp32 -> bf16 conversion + Acoef setup + l2 zero --------
struct CvtArgs {
    const float* src[7];
    unsigned short* dst[7];
    int n4[7];
};
__global__ __launch_bounds__(256)
void cvt_all(CvtArgs a, int total4, const float* __restrict__ Alog,
             float* __restrict__ Ac, float* l2)
{
    int i = blockIdx.x * 256 + threadIdx.x;
    if (i >= total4) {
        int j = i - total4;
        if (j < 16384) Ac[j] = -__expf(Alog[j]);
        if (j == 0) *l2 = 0.0f;
        return;
    }
    int seg = 0;
    while (i >= a.n4[seg]) { i -= a.n4[seg]; seg++; }
    float4 v = reinterpret_cast<const float4*>(a.src[seg])[i];
    ushort4 o;
    o.x = bf16bits(v.x); o.y = bf16bits(v.y); o.z = bf16bits(v.z); o.w = bf16bits(v.w);
    reinterpret_cast<ushort4*>(a.dst[seg])[i] = o;
}

// ---------------- generic MFMA bf16 GEMM (64x64 tile) ----------------
__global__ __launch_bounds__(256)
void gemm_mfma(const unsigned short* __restrict__ A,
               const unsigned short* __restrict__ W,
               const float* __restrict__ bias,
               float* __restrict__ C,
               int N, int K)
{
    __shared__ __align__(16) unsigned short As[64][40];
    __shared__ __align__(16) unsigned short Bs[64][40];

    const int tid = threadIdx.x;
    const int wid = tid >> 6, lane = tid & 63;
    const int wm = (wid >> 1) * 32, wn = (wid & 1) * 32;
    const int m0 = blockIdx.y * 64, n0 = blockIdx.x * 64;
    const int lrow = lane & 15, quad = lane >> 4;

    const int sm = tid >> 2;
    const int sk = (tid & 3) * 8;

    f32x4 acc[2][2] = {};

    for (int k0 = 0; k0 < K; k0 += 32) {
        float4 av = *reinterpret_cast<const float4*>(A + (size_t)(m0 + sm) * K + k0 + sk);
        *reinterpret_cast<float4*>(&As[sm][sk]) = av;
        float4 bv = {0.f, 0.f, 0.f, 0.f};
        int n = n0 + sm;
        if (n < N) bv = *reinterpret_cast<const float4*>(W + (size_t)n * K + k0 + sk);
        *reinterpret_cast<float4*>(&Bs[sm][sk]) = bv;
        __syncthreads();

        frag8 a0 = *reinterpret_cast<const frag8*>(&As[wm + lrow][quad * 8]);
        frag8 a1 = *reinterpret_cast<const frag8*>(&As[wm + 16 + lrow][quad * 8]);
        frag8 b0 = *reinterpret_cast<const frag8*>(&Bs[wn + lrow][quad * 8]);
        frag8 b1 = *reinterpret_cast<const frag8*>(&Bs[wn + 16 + lrow][quad * 8]);

        acc[0][0] = __builtin_amdgcn_mfma_f32_16x16x32_bf16(a0, b0, acc[0][0], 0, 0, 0);
        acc[0][1] = __builtin_amdgcn_mfma_f32_16x16x32_bf16(a0, b1, acc[0][1], 0, 0, 0);
        acc[1][0] = __builtin_amdgcn_mfma_f32_16x16x32_bf16(a1, b0, acc[1][0], 0, 0, 0);
        acc[1][1] = __builtin_amdgcn_mfma_f32_16x16x32_bf16(a1, b1, acc[1][1], 0, 0, 0);
        __syncthreads();
    }

    #pragma unroll
    for (int mi = 0; mi < 2; mi++) {
        #pragma unroll
        for (int nj = 0; nj < 2; nj++) {
            int col = n0 + wn + nj * 16 + lrow;
            if (col >= N) continue;
            #pragma unroll
            for (int r = 0; r < 4; r++) {
                int row = m0 + wm + mi * 16 + quad * 4 + r;
                float v = acc[mi][nj][r];
                if (bias) v += bias[col];
                C[(size_t)row * N + col] = v;
            }
        }
    }
}

// ---------------- ipw GEMM (N=1024, K=256): u-half -> xzuT fp32 [b][d][t],
// ---------------- z-half -> silu(z) bf16 szT [b][d][t] ----------------
__global__ __launch_bounds__(256)
void gemm_ipw(const unsigned short* __restrict__ A,
              const unsigned short* __restrict__ W,
              float* __restrict__ xzuT,
              unsigned short* __restrict__ szT)
{
    __shared__ __align__(16) unsigned short As[64][40];
    __shared__ __align__(16) unsigned short Bs[64][40];

    const int tid = threadIdx.x;
    const int wid = tid >> 6, lane = tid & 63;
    const int wm = (wid >> 1) * 32, wn = (wid & 1) * 32;
    const int m0 = blockIdx.y * 64, n0 = blockIdx.x * 64;
    const int lrow = lane & 15, quad = lane >> 4;
    const int K = 256;

    const int sm = tid >> 2;
    const int sk = (tid & 3) * 8;

    f32x4 acc[2][2] = {};

    for (int k0 = 0; k0 < K; k0 += 32) {
        float4 av = *reinterpret_cast<const float4*>(A + (size_t)(m0 + sm) * K + k0 + sk);
        *reinterpret_cast<float4*>(&As[sm][sk]) = av;
        float4 bv = *reinterpret_cast<const float4*>(W + (size_t)(n0 + sm) * K + k0 + sk);
        *reinterpret_cast<float4*>(&Bs[sm][sk]) = bv;
        __syncthreads();

        frag8 a0 = *reinterpret_cast<const frag8*>(&As[wm + lrow][quad * 8]);
        frag8 a1 = *reinterpret_cast<const frag8*>(&As[wm + 16 + lrow][quad * 8]);
        frag8 b0 = *reinterpret_cast<const frag8*>(&Bs[wn + lrow][quad * 8]);
        frag8 b1 = *reinterpret_cast<const frag8*>(&Bs[wn + 16 + lrow][quad * 8]);

        acc[0][0] = __builtin_amdgcn_mfma_f32_16x16x32_bf16(a0, b0, acc[0][0], 0, 0, 0);
        acc[0][1] = __builtin_amdgcn_mfma_f32_16x16x32_bf16(a0, b1, acc[0][1], 0, 0, 0);
        acc[1][0] = __builtin_amdgcn_mfma_f32_16x16x32_bf16(a1, b0, acc[1][0], 0, 0, 0);
        acc[1][1] = __builtin_amdgcn_mfma_f32_16x16x32_bf16(a1, b1, acc[1][1], 0, 0, 0);
        __syncthreads();
    }

    // epilogue: transposed stores. row = t (within batch), col = output channel.
    const int bb = m0 >> 10;
    const int tb = m0 & 1023;
    #pragma unroll
    for (int mi = 0; mi < 2; mi++) {
        int t4 = tb + wm + mi * 16 + quad * 4;     // 4 consecutive t's
        #pragma unroll
        for (int nj = 0; nj < 2; nj++) {
            int col = n0 + wn + nj * 16 + lrow;
            if (col < 512) {
                float4 o = { acc[mi][nj][0], acc[mi][nj][1], acc[mi][nj][2], acc[mi][nj][3] };
                *reinterpret_cast<float4*>(xzuT + ((size_t)(bb * 512 + col)) * 1024 + t4) = o;
            } else {
                int z = col - 512;
                ushort4 o;
                float v0 = acc[mi][nj][0], v1 = acc[mi][nj][1], v2 = acc[mi][nj][2], v3 = acc[mi][nj][3];
                o.x = bf16bits(v0 * sigmoid_f(v0));
                o.y = bf16bits(v1 * sigmoid_f(v1));
                o.z = bf16bits(v2 * sigmoid_f(v2));
                o.w = bf16bits(v3 * sigmoid_f(v3));
                *reinterpret_cast<ushort4*>(szT + ((size_t)(bb * 512 + z)) * 1024 + t4) = o;
            }
        }
    }
}

// ---------------- MFMA GEMM, A from ucT [B=4][K=512][T=1024] fp32 ---------------
__global__ __launch_bounds__(256)
void gemm_at(const float* __restrict__ AT,
             const unsigned short* __restrict__ W,
             float* __restrict__ C,
             int N, int K)
{
    __shared__ __align__(16) unsigned short As[64][40];
    __shared__ __align__(16) unsigned short Bs[64][40];

    const int tid = threadIdx.x;
    const int wid = tid >> 6, lane = tid & 63;
    const int wm = (wid >> 1) * 32, wn = (wid & 1) * 32;
    const int m0 = blockIdx.y * 64;
    const int bb = m0 >> 10;
    const int tb = m0 & 1023;
    const int lrow = lane & 15, quad = lane >> 4;

    const int sm = tid >> 2;
    const int sk = (tid & 3) * 8;

    f32x4 acc[2][2] = {};

    for (int k0 = 0; k0 < K; k0 += 32) {
        #pragma unroll
        for (int p = 0; p < 2; p++) {
            int kk = (tid >> 4) + p * 16;
            int mq = tid & 15;
            float4 v = *reinterpret_cast<const float4*>(AT + ((size_t)(bb * 512 + k0 + kk)) * 1024 + tb + mq * 4);
            As[mq * 4 + 0][kk] = bf16bits(v.x);
            As[mq * 4 + 1][kk] = bf16bits(v.y);
            As[mq * 4 + 2][kk] = bf16bits(v.z);
            As[mq * 4 + 3][kk] = bf16bits(v.w);
        }
        float4 bv = {0.f, 0.f, 0.f, 0.f};
        if (sm < N) bv = *reinterpret_cast<const float4*>(W + (size_t)sm * K + k0 + sk);
        *reinterpret_cast<float4*>(&Bs[sm][sk]) = bv;
        __syncthreads();

        frag8 a0 = *reinterpret_cast<const frag8*>(&As[wm + lrow][quad * 8]);
        frag8 a1 = *reinterpret_cast<const frag8*>(&As[wm + 16 + lrow][quad * 8]);
        frag8 b0 = *reinterpret_cast<const frag8*>(&Bs[wn + lrow][quad * 8]);
        frag8 b1 = *reinterpret_cast<const frag8*>(&Bs[wn + 16 + lrow][quad * 8]);

        acc[0][0] = __builtin_amdgcn_mfma_f32_16x16x32_bf16(a0, b0, acc[0][0], 0, 0, 0);
        acc[0][1] = __builtin_amdgcn_mfma_f32_16x16x32_bf16(a0, b1, acc[0][1], 0, 0, 0);
        acc[1][0] = __builtin_amdgcn_mfma_f32_16x16x32_bf16(a1, b0, acc[1][0], 0, 0, 0);
        acc[1][1] = __builtin_amdgcn_mfma_f32_16x16x32_bf16(a1, b1, acc[1][1], 0, 0, 0);
        __syncthreads();
    }

    #pragma unroll
    for (int mi = 0; mi < 2; mi++) {
        #pragma unroll
        for (int nj = 0; nj < 2; nj++) {
            int col = wn + nj * 16 + lrow;
            if (col >= N) continue;
            #pragma unroll
            for (int r = 0; r < 4; r++) {
                int row = m0 + wm + mi * 16 + quad * 4 + r;
                C[(size_t)row * N + col] = acc[mi][nj][r];
            }
        }
    }
}

// ---------------- full-row GEMM (N=256) fused LN / GELU / res / L2 --------------
__global__ __launch_bounds__(256)
void rowgemm(const unsigned short* __restrict__ A,
             const unsigned short* __restrict__ W,
             const float* __restrict__ bias,
             const float* res,
             const float* g1, const float* b1, int gelu1,
             const float* g2, const float* b2,
             float* outF, unsigned short* outB, float* l2out, int K)
{
    __shared__ __align__(16) unsigned short As[16][40];
    __shared__ __align__(16) unsigned short Bs[256][40];
    __shared__ float red[4][16][2];
    __shared__ float sq[16];

    const int tid = threadIdx.x;
    const int w = tid >> 6, lane = tid & 63;
    const int lrow = lane & 15, quad = lane >> 4;
    const int m0 = blockIdx.x * 16;

    f32x4 acc[4] = {};

    for (int k0 = 0; k0 < K; k0 += 32) {
        if (tid < 64) {
            float4 av = *reinterpret_cast<const float4*>(A + (size_t)(m0 + (tid >> 2)) * K + k0 + (tid & 3) * 8);
            *reinterpret_cast<float4*>(&As[tid >> 2][(tid & 3) * 8]) = av;
        }
        #pragma unroll
        for (int i = 0; i < 4; i++) {
            int n = (tid >> 2) + i * 64;
            float4 bv = *reinterpret_cast<const float4*>(W + (size_t)n * K + k0 + (tid & 3) * 8);
            *reinterpret_cast<float4*>(&Bs[n][(tid & 3) * 8]) = bv;
        }
        __syncthreads();
        frag8 a = *reinterpret_cast<const frag8*>(&As[lrow][quad * 8]);
        #pragma unroll
        for (int nj = 0; nj < 4; nj++) {
            frag8 b = *reinterpret_cast<const frag8*>(&Bs[w * 64 + nj * 16 + lrow][quad * 8]);
            acc[nj] = __builtin_amdgcn_mfma_f32_16x16x32_bf16(a, b, acc[nj], 0, 0, 0);
        }
        __syncthreads();
    }

    float v[4][4];
    #pragma unroll
    for (int nj = 0; nj < 4; nj++) {
        int col = w * 64 + nj * 16 + lrow;
        #pragma unroll
        for (int r = 0; r < 4; r++) {
            int row = m0 + quad * 4 + r;
            float t = acc[nj][r];
            if (bias) t += bias[col];
            if (res) t += res[(size_t)row * 256 + col];
            v[nj][r] = t;
        }
    }

    if (g1) {
        #pragma unroll
        for (int r = 0; r < 4; r++) {
            float s1 = v[0][r] + v[1][r] + v[2][r] + v[3][r];
            float s2 = v[0][r]*v[0][r] + v[1][r]*v[1][r] + v[2][r]*v[2][r] + v[3][r]*v[3][r];
            s1 = row_sum16(s1); s2 = row_sum16(s2);
            if (lrow == 0) { red[w][quad * 4 + r][0] = s1; red[w][quad * 4 + r][1] = s2; }
        }
        __syncthreads();
        #pragma unroll
        for (int r = 0; r < 4; r++) {
            int rr = quad * 4 + r;
            float t1 = red[0][rr][0] + red[1][rr][0] + red[2][rr][0] + red[3][rr][0];
            float t2 = red[0][rr][1] + red[1][rr][1] + red[2][rr][1] + red[3][rr][1];
            float mu = t1 * (1.0f / 256.0f);
            float var = t2 * (1.0f / 256.0f) - mu * mu;
            float rstd = rsqrtf(var + 1e-5f);
            #pragma unroll
            for (int nj = 0; nj < 4; nj++) {
                int col = w * 64 + nj * 16 + lrow;
                float t = (v[nj][r] - mu) * rstd * g1[col] + b1[col];
                if (gelu1) t = gelu_exact(t);
                v[nj][r] = t;
            }
        }
        __syncthreads();
    } else if (gelu1) {
        #pragma unroll
        for (int nj = 0; nj < 4; nj++)
            #pragma unroll
            for (int r = 0; r < 4; r++)
                v[nj][r] = gelu_exact(v[nj][r]);
    }

    if (outF) {
        #pragma unroll
        for (int nj = 0; nj < 4; nj++) {
            int col = w * 64 + nj * 16 + lrow;
            #pragma unroll
            for (int r = 0; r < 4; r++)
                outF[(size_t)(m0 + quad * 4 + r) * 256 + col] = v[nj][r];
        }
    }

    if (l2out) {
        #pragma unroll
        for (int r = 0; r < 4; r++) {
            float s2 = v[0][r]*v[0][r] + v[1][r]*v[1][r] + v[2][r]*v[2][r] + v[3][r]*v[3][r];
            s2 = row_sum16(s2);
            if (lrow == 0) red[w][quad * 4 + r][0] = s2;
        }
        __syncthreads();
        if (tid < 16) {
            float t = red[0][tid][0] + red[1][tid][0] + red[2][tid][0] + red[3][tid][0];
            sq[tid] = sqrtf(t);
        }
        __syncthreads();
        if (tid == 0) {
            float a = 0.f;
            #pragma unroll
            for (int i = 0; i < 16; i++) a += sq[i];
            atomicAdd(l2out, a * (0.01f / 4096.0f));
        }
    }

    if (g2) {
        __syncthreads();
        #pragma unroll
        for (int r = 0; r < 4; r++) {
            float s1 = v[0][r] + v[1][r] + v[2][r] + v[3][r];
            float s2 = v[0][r]*v[0][r] + v[1][r]*v[1][r] + v[2][r]*v[2][r] + v[3][r]*v[3][r];
            s1 = row_sum16(s1); s2 = row_sum16(s2);
            if (lrow == 0) { red[w][quad * 4 + r][0] = s1; red[w][quad * 4 + r][1] = s2; }
        }
        __syncthreads();
        #pragma unroll
        for (int r = 0; r < 4; r++) {
            int rr = quad * 4 + r;
            float t1 = red[0][rr][0] + red[1][rr][0] + red[2][rr][0] + red[3][rr][0];
            float t2 = red[0][rr][1] + red[1][rr][1] + red[2][rr][1] + red[3][rr][1];
            float mu = t1 * (1.0f / 256.0f);
            float var = t2 * (1.0f / 256.0f) - mu * mu;
            float rstd = rsqrtf(var + 1e-5f);
            #pragma unroll
            for (int nj = 0; nj < 4; nj++) {
                int col = w * 64 + nj * 16 + lrow;
                outB[(size_t)(m0 + rr) * 256 + col] = bf16bits((v[nj][r] - mu) * rstd * g2[col] + b2[col]);
            }
        }
    } else if (outB) {
        #pragma unroll
        for (int nj = 0; nj < 4; nj++) {
            int col = w * 64 + nj * 16 + lrow;
            #pragma unroll
            for (int r = 0; r < 4; r++)
                outB[(size_t)(m0 + quad * 4 + r) * 256 + col] = bf16bits(v[nj][r]);
        }
    }
}

// ---------------- causal conv4 + bias + SiLU on transposed u ---------------------
// reads xzuT [b][d][t] fp32, writes ucT [b][d][t] fp32. grid 512: b(4) x dtile(8) x tt(16)
__global__ __launch_bounds__(256)
void conv_T(const float* __restrict__ xzuT, const float* __restrict__ cw,
            const float* __restrict__ cb, float* __restrict__ ucT)
{
    __shared__ float xs[64][68];
    const int bx = blockIdx.x;
    const int b = bx >> 7;
    const int dt_ = (bx >> 4) & 7;
    const int tt = bx & 15;
    const int tid = threadIdx.x;
    const int d0 = dt_ * 64, t0 = tt * 64;

    // load 64 d-rows x 67 t-cols (t0-3 .. t0+63), zero-pad t<0
    {
        const int dd = tid >> 2;
        const int c0_ = (tid & 3) * 17;
        const float* src = xzuT + ((size_t)(b * 512 + d0 + dd)) * 1024 + t0 - 3;
        #pragma unroll
        for (int k = 0; k < 17; k++) {
            int tc = c0_ + k;
            if (tc < 67) {
                int tg = t0 - 3 + tc;
                xs[dd][tc] = (tg >= 0) ? src[tc] : 0.0f;
            }
        }
    }
    __syncthreads();

    const int tl = tid & 63, dgrp = tid >> 6;
    #pragma unroll 4
    for (int dp = 0; dp < 16; dp++) {
        int dd = dp * 4 + dgrp;
        int d = d0 + dd;
        float c0 = cw[d * 4 + 0], c1 = cw[d * 4 + 1], c2 = cw[d * 4 + 2], c3 = cw[d * 4 + 3];
        float acc = cb[d] + xs[dd][tl] * c0 + xs[dd][tl + 1] * c1 + xs[dd][tl + 2] * c2 + xs[dd][tl + 3] * c3;
        ucT[((size_t)(b * 512 + d)) * 1024 + t0 + tl] = acc * sigmoid_f(acc);
    }
}

// ---------------- dt proj + softplus -> dltT ; fused B/C transpose --------------
__global__ __launch_bounds__(256)
void dtbc(const float* __restrict__ xdbc, const float* __restrict__ dtw,
          const float* __restrict__ dtb, float* __restrict__ dltT,
          float* __restrict__ BT, float* __restrict__ CT)
{
    __shared__ float xd[64][17];
    __shared__ float wS[64][16];
    __shared__ float bS[64];
    const int bx = blockIdx.x;
    const int b = bx >> 7;
    const int tt = (bx >> 3) & 15;
    const int dg = bx & 7;
    const int tid = threadIdx.x;
    const int t0 = tt * 64, d0 = dg * 64;

    for (int i = tid; i < 64 * 16; i += 256) {
        int t = i >> 4, k = i & 15;
        xd[t][k] = xdbc[((size_t)(b * 1024 + t0 + t)) * 48 + k];
    }
    for (int i = tid; i < 64 * 16; i += 256) {
        int dl = i >> 4, k = i & 15;
        wS[dl][k] = dtw[(d0 + dl) * 16 + k];
    }
    if (tid < 64) bS[tid] = dtb[d0 + tid];
    __syncthreads();

    const int tl = tid & 63, w = tid >> 6;
    #pragma unroll 4
    for (int di = 0; di < 16; di++) {
        int dl = w * 16 + di;
        float acc = bS[dl];
        #pragma unroll
        for (int k = 0; k < 16; k++) acc += xd[tl][k] * wS[dl][k];
        dltT[((size_t)(b * 512 + d0 + dl)) * 1024 + t0 + tl] = softplus_f(acc);
    }

    {
        int c = tid >> 6;
        int t = tid & 63;
        int col = dg * 4 + c;
        float v = xdbc[((size_t)(b * 1024 + t0 + t)) * 48 + 16 + col];
        if (col < 16) BT[((size_t)(b * 16 + col)) * 1024 + t0 + t] = v;
        else          CT[((size_t)(b * 16 + col - 16)) * 1024 + t0 + t] = v;
    }
}

// ---------------- chunked selective scan (1 barrier, decentralized combine) -----
__global__ __launch_bounds__(1024)
void scan_chunked(const float* __restrict__ dltT, const float* __restrict__ ucT,
                  const float* __restrict__ BT, const float* __restrict__ CT,
                  const unsigned short* __restrict__ szT,
                  const float* __restrict__ Ac,
                  const float* __restrict__ Dp,
                  unsigned short* __restrict__ y)
{
    __shared__ float aprod_s[16][64];
    __shared__ float sfin_s[16][64];
    __shared__ float sin_w[16][64];
    __shared__ __align__(16) float ylocal[16][64][4];

    const int j = blockIdx.x;
    const int bid = (j & 7) * 64 + (j >> 3);     // XCD swizzle
    const int b = bid >> 7;
    const int d0 = (bid & 127) * 4;
    const int w = threadIdx.x >> 6;
    const int lane = threadIdx.x & 63;
    const int dsub = lane >> 4, s = lane & 15;
    const int d = d0 + dsub;

    const float Acoef = Ac[d * 16 + s];

    const float4* dp = reinterpret_cast<const float4*>(dltT + ((size_t)(b * 512 + d)) * 1024 + w * 64);
    const float4* up = reinterpret_cast<const float4*>(ucT  + ((size_t)(b * 512 + d)) * 1024 + w * 64);
    const float4* Bp = reinterpret_cast<const float4*>(BT + ((size_t)(b * 16 + s)) * 1024 + w * 64);
    const float4* Cp = reinterpret_cast<const float4*>(CT + ((size_t)(b * 16 + s)) * 1024 + w * 64);

    // ---- Phase A: local scan with cumprod (q+1 prefetch) ----
    float st = 0.0f, ap = 1.0f;
    float4 dt4 = dp[0], ut4 = up[0], B4 = Bp[0], C4 = Cp[0];
    #pragma unroll
    for (int q = 0; q < 16; q++) {
        float4 ndt, nut, nB, nC;
        if (q < 15) { ndt = dp[q + 1]; nut = up[q + 1]; nB = Bp[q + 1]; nC = Cp[q + 1]; }
        const float* dtp = (const float*)&dt4;
        const float* utp = (const float*)&ut4;
        const float* Btp = (const float*)&B4;
        const float* Ctp = (const float*)&C4;
        #pragma unroll
        for (int jj = 0; jj < 4; jj++) {
            float dA = __expf(dtp[jj] * Acoef);
            st = st * dA + dtp[jj] * utp[jj] * Btp[jj];
            ap *= dA;
            float part = row_sum16(st * Ctp[jj]);
            if (s == 0) ylocal[w][q * 4 + jj][dsub] = part;
        }
        dt4 = ndt; ut4 = nut; B4 = nB; C4 = nC;
    }
    aprod_s[w][lane] = ap;
    sfin_s[w][lane] = st;
    __syncthreads();                                 // the only barrier

    // ---- decentralized combine ----
    {
        float pre = 0.0f;
        #pragma unroll
        for (int c = 0; c < 15; c++) {
            float apc = aprod_s[c][lane];
            float sfc = sfin_s[c][lane];
            float cand = sfc + apc * pre;
            pre = (c < w) ? cand : pre;
        }
        sin_w[w][lane] = pre;
    }

    // ---- Phase C: lane = t; correction via prefix sums + epilogue ----
    const int t = w * 64 + lane;
    float cums[4];
    #pragma unroll
    for (int dd = 0; dd < 4; dd++)
        cums[dd] = dltT[((size_t)(b * 512 + d0 + dd)) * 1024 + t];
    #pragma unroll
    for (int dd = 0; dd < 4; dd++)
        cums[dd] = prefix_sum64(cums[dd]);

    float4 yl = *reinterpret_cast<const float4*>(&ylocal[w][lane][0]);
    float acc[4] = { yl.x, yl.y, yl.z, yl.w };

    #pragma unroll
    for (int sq = 0; sq < 4; sq++) {
        float Cs[4];
        #pragma unroll
        for (int jj = 0; jj < 4; jj++)
            Cs[jj] = CT[((size_t)(b * 16 + sq * 4 + jj)) * 1024 + t];
        #pragma unroll
        for (int dd = 0; dd < 4; dd++) {
            float4 sin4 = *reinterpret_cast<const float4*>(&sin_w[w][dd * 16 + sq * 4]);
            const float* sp = (const float*)&sin4;
            #pragma unroll
            for (int jj = 0; jj < 4; jj++) {
                float ac = Ac[(d0 + dd) * 16 + sq * 4 + jj];
                acc[dd] += sp[jj] * Cs[jj] * __expf(ac * cums[dd]);
            }
        }
    }

    const size_t row = (size_t)b * 1024 + t;
    #pragma unroll
    for (int dd = 0; dd < 4; dd++) {
        float ut = ucT[((size_t)(b * 512 + d0 + dd)) * 1024 + t];
        float sz = bf2f(szT[((size_t)(b * 512 + d0 + dd)) * 1024 + t]);
        float yv = acc[dd] + ut * Dp[d0 + dd];
        y[row * 512 + d0 + dd] = bf16bits(yv * sz);
    }
}

// ---------------- launcher ----------------
extern "C" void kernel_launch(void* const* d_in, const int* in_sizes, int n_in,
                              void* d_out, int out_size, void* d_ws, size_t ws_size,
                              hipStream_t stream)
{
    const float* x      = (const float*)d_in[0];
    const float* in_b   = (const float*)d_in[2];
    const float* ln_g   = (const float*)d_in[3];
    const float* ln_b   = (const float*)d_in[4];
    const float* blk_ng  = (const float*)d_in[5];
    const float* blk_nb  = (const float*)d_in[6];
    const float* blk_cw  = (const float*)d_in[8];
    const float* blk_cb  = (const float*)d_in[9];
    const float* blk_dtw = (const float*)d_in[11];
    const float* blk_dtb = (const float*)d_in[12];
    const float* blk_Alog= (const float*)d_in[13];
    const float* blk_D   = (const float*)d_in[14];
    const float* op_b   = (const float*)d_in[17];
    const float* cls_b  = (const float*)d_in[19];
    float* out = (float*)d_out;

    const int BL = 4096;
    float* ws = (float*)d_ws;
    float* h0   = ws;                         // 1,048,576
    float* xzuT = h0 + 1048576;               // 2,097,152  [b][d][t] fp32 (u pre-conv)
    float* ucT  = xzuT + 2097152;             // 2,097,152  [b][d][t]
    float* xdbc = ucT + 2097152;              //   196,608
    float* dltT = xdbc + 196608;              // 2,097,152  [b][d][t]
    float* BT   = dltT + 2097152;             //    65,536  [b][s][t]
    float* CT   = BT + 65536;                 //    65,536  [b][s][t]
    float* Ac   = CT + 65536;                 //    16,384
    unsigned short* szT = (unsigned short*)(Ac + 16384);  // 2,097,152 bf16 [b][d][t]
    unsigned short* wb  = szT + 2097152;      // 1,130,496
    unsigned short* hnb = wb + 1130496;       // 1,048,576
    unsigned short* ybb = hnb + 1048576;      // 2,097,152
    unsigned short* xb  = (unsigned short*)dltT;  // x bf16 (dead before dltT written)
    unsigned short* h0b = hnb;
    unsigned short* h2b = ybb;
    unsigned short* in_wb  = wb;
    unsigned short* ipw_b  = wb + 196608;
    unsigned short* xpw_b  = wb + 720896;
    unsigned short* opw_b  = wb + 770048;
    unsigned short* op_wb  = wb + 1032192;
    unsigned short* cls_wb = wb + 1097728;

    CvtArgs ca;
    ca.src[0] = x;                  ca.dst[0] = xb;     ca.n4[0] = 3145728 / 4;
    ca.src[1] = (const float*)d_in[1];  ca.dst[1] = in_wb;  ca.n4[1] = 196608 / 4;
    ca.src[2] = (const float*)d_in[7];  ca.dst[2] = ipw_b;  ca.n4[2] = 524288 / 4;
    ca.src[3] = (const float*)d_in[10]; ca.dst[3] = xpw_b;  ca.n4[3] = 49152 / 4;
    ca.src[4] = (const float*)d_in[15]; ca.dst[4] = opw_b;  ca.n4[4] = 262144 / 4;
    ca.src[5] = (const float*)d_in[16]; ca.dst[5] = op_wb;  ca.n4[5] = 65536 / 4;
    ca.src[6] = (const float*)d_in[18]; ca.dst[6] = cls_wb; ca.n4[6] = 32768 / 4;
    int total4 = (3145728 + 1130496) / 4;
    int totalg = total4 + 16384;
    cvt_all<<<(totalg + 255) / 256, 256, 0, stream>>>(ca, total4, blk_Alog, Ac,
                                                      out + (size_t)BL * 128);

    // in_proj + bias + LN + GELU -> h0 (fp32), + LN(layer0) -> hnb (bf16)
    rowgemm<<<256, 256, 0, stream>>>(xb, in_wb, in_b, nullptr,
                                     ln_g, ln_b, 1,
                                     blk_ng, blk_nb,
                                     h0, hnb, nullptr, 768);

    for (int l = 0; l < 2; l++) {
        const float* cw   = blk_cw  + (size_t)l * 512 * 4;
        const float* cb   = blk_cb  + l * 512;
        const float* dtw  = blk_dtw + (size_t)l * 512 * 16;
        const float* dtb  = blk_dtb + l * 512;
        const float* Dl   = blk_D   + l * 512;
        const unsigned short* ipwl = ipw_b + (size_t)l * 262144;
        const unsigned short* xpwl = xpw_b + (size_t)l * 24576;
        const unsigned short* opwl = opw_b + (size_t)l * 131072;

        // ipw GEMM: u -> xzuT fp32 [b][d][t]; z -> silu(z) bf16 szT [b][d][t]
        gemm_ipw<<<dim3(16, 64), 256, 0, stream>>>(hnb, ipwl, xzuT, szT);
        // ucT = silu(conv(u)+cb) [b][d][t]
        conv_T<<<512, 256, 0, stream>>>(xzuT, cw, cb, ucT);
        // xdbc = u @ xpw.T  (N=48, K=512), A read from ucT [b][k][t]
        gemm_at<<<dim3(1, 64), 256, 0, stream>>>(ucT, xpwl, xdbc, 48, 512);
        // dltT (softplus) + fused BT/CT transpose
        dtbc<<<512, 256, 0, stream>>>(xdbc, dtw, dtb, dltT, BT, CT);
        // scan -> ybb
        scan_chunked<<<512, 1024, 0, stream>>>(dltT, ucT, BT, CT, szT,
                                               Ac + (size_t)l * 8192, Dl, ybb);
        // h0 += ybb @ opw.T; layer0: +LN(layer1)->hnb; layer1: ->h0b bf16 only
        if (l == 0)
            rowgemm<<<256, 256, 0, stream>>>(ybb, opwl, nullptr, h0,
                                             nullptr, nullptr, 0,
                                             blk_ng + 256, blk_nb + 256,
                                             h0, hnb, nullptr, 512);
        else
            rowgemm<<<256, 256, 0, stream>>>(ybb, opwl, nullptr, h0,
                                             nullptr, nullptr, 0,
                                             nullptr, nullptr,
                                             nullptr, h0b, nullptr, 512);
    }

    // h2 = gelu(h0b @ op_w.T + op_b) -> h2b (bf16) + fused L2 scalar
    rowgemm<<<256, 256, 0, stream>>>(h0b, op_wb, op_b, nullptr,
                                     nullptr, nullptr, 1,
                                     nullptr, nullptr,
                                     nullptr, h2b, out + (size_t)BL * 128, 256);
    // logits = h2b @ cls_w.T + cls_b -> d_out (N=128, K=256)
    gemm_mfma<<<dim3(2, 64), 256, 0, stream>>>(h2b, cls_wb, cls_b, out, 128, 256);
}

// Round 12
// 349.555 us; speedup vs baseline: 1.1966x; 1.0336x over previous
//
#include <hip/hip_runtime.h>
#include <hip/hip_bf16.h>
#include <math.h>

typedef __attribute__((ext_vector_type(8))) short frag8;   // 8 bf16 (4 VGPRs)
typedef __attribute__((ext_vector_type(4))) float f32x4;

// ---------------- device helpers ----------------
__device__ __forceinline__ float gelu_exact(float x) {
    return 0.5f * x * (1.0f + erff(x * 0.70710678118654752f));
}
__device__ __forceinline__ float softplus_f(float x) {
    return (x > 20.0f) ? x : log1pf(expf(x));
}
__device__ __forceinline__ float sigmoid_f(float x) {
    return 1.0f / (1.0f + __expf(-x));
}
__device__ __forceinline__ unsigned short bf16bits(float x) {
    __hip_bfloat16 h = __float2bfloat16(x);
    return *(unsigned short*)&h;
}
__device__ __forceinline__ float bf2f(unsigned short u) {
    unsigned int v = ((unsigned int)u) << 16;
    return __builtin_bit_cast(float, v);
}
// sum over the 16 lanes of each DPP row-of-16 — VALU-pipe only
__device__ __forceinline__ float row_sum16(float x) {
    int t;
    t = __builtin_amdgcn_update_dpp(0, __builtin_bit_cast(int, x), 0x128, 0xf, 0xf, true); // row_ror:8
    x += __builtin_bit_cast(float, t);
    t = __builtin_amdgcn_update_dpp(0, __builtin_bit_cast(int, x), 0x124, 0xf, 0xf, true); // row_ror:4
    x += __builtin_bit_cast(float, t);
    t = __builtin_amdgcn_update_dpp(0, __builtin_bit_cast(int, x), 0x122, 0xf, 0xf, true); // row_ror:2
    x += __builtin_bit_cast(float, t);
    t = __builtin_amdgcn_update_dpp(0, __builtin_bit_cast(int, x), 0x121, 0xf, 0xf, true); // row_ror:1
    x += __builtin_bit_cast(float, t);
    return x;
}
// inclusive prefix sum over the full 64-lane wave (DPP, VALU-pipe only)
__device__ __forceinline__ float prefix_sum64(float x) {
    int t;
    t = __builtin_amdgcn_update_dpp(0, __builtin_bit_cast(int, x), 0x111, 0xf, 0xf, true); // row_shr:1
    x += __builtin_bit_cast(float, t);
    t = __builtin_amdgcn_update_dpp(0, __builtin_bit_cast(int, x), 0x112, 0xf, 0xf, true); // row_shr:2
    x += __builtin_bit_cast(float, t);
    t = __builtin_amdgcn_update_dpp(0, __builtin_bit_cast(int, x), 0x114, 0xf, 0xf, true); // row_shr:4
    x += __builtin_bit_cast(float, t);
    t = __builtin_amdgcn_update_dpp(0, __builtin_bit_cast(int, x), 0x118, 0xf, 0xf, true); // row_shr:8
    x += __builtin_bit_cast(float, t);
    t = __builtin_amdgcn_update_dpp(0, __builtin_bit_cast(int, x), 0x142, 0xa, 0xf, true); // row_bcast:15
    x += __builtin_bit_cast(float, t);
    t = __builtin_amdgcn_update_dpp(0, __builtin_bit_cast(int, x), 0x143, 0xc, 0xf, true); // row_bcast:31
    x += __builtin_bit_cast(float, t);
    return x;
}

// ---------------- fused fp32 -> bf16 conversion + Acoef setup + l2 zero --------
struct CvtArgs {
    const float* src[7];
    unsigned short* dst[7];
    int n4[7];
};
__global__ __launch_bounds__(256)
void cvt_all(CvtArgs a, int total4, const float* __restrict__ Alog,
             float* __restrict__ Ac, float* l2)
{
    int i = blockIdx.x * 256 + threadIdx.x;
    if (i >= total4) {
        int j = i - total4;
        if (j < 16384) Ac[j] = -__expf(Alog[j]);
        if (j == 0) *l2 = 0.0f;
        return;
    }
    int seg = 0;
    while (i >= a.n4[seg]) { i -= a.n4[seg]; seg++; }
    float4 v = reinterpret_cast<const float4*>(a.src[seg])[i];
    ushort4 o;
    o.x = bf16bits(v.x); o.y = bf16bits(v.y); o.z = bf16bits(v.z); o.w = bf16bits(v.w);
    reinterpret_cast<ushort4*>(a.dst[seg])[i] = o;
}

// ---------------- ipw GEMM (N=1024, K=256): u-half -> xzuT fp32 [b][d][t],
// ---------------- z-half -> silu(z) bf16 szT [b][d][t] ----------------
__global__ __launch_bounds__(256)
void gemm_ipw(const unsigned short* __restrict__ A,
              const unsigned short* __restrict__ W,
              float* __restrict__ xzuT,
              unsigned short* __restrict__ szT)
{
    __shared__ __align__(16) unsigned short As[64][40];
    __shared__ __align__(16) unsigned short Bs[64][40];

    const int tid = threadIdx.x;
    const int wid = tid >> 6, lane = tid & 63;
    const int wm = (wid >> 1) * 32, wn = (wid & 1) * 32;
    const int m0 = blockIdx.y * 64, n0 = blockIdx.x * 64;
    const int lrow = lane & 15, quad = lane >> 4;
    const int K = 256;

    const int sm = tid >> 2;
    const int sk = (tid & 3) * 8;

    f32x4 acc[2][2] = {};

    for (int k0 = 0; k0 < K; k0 += 32) {
        float4 av = *reinterpret_cast<const float4*>(A + (size_t)(m0 + sm) * K + k0 + sk);
        *reinterpret_cast<float4*>(&As[sm][sk]) = av;
        float4 bv = *reinterpret_cast<const float4*>(W + (size_t)(n0 + sm) * K + k0 + sk);
        *reinterpret_cast<float4*>(&Bs[sm][sk]) = bv;
        __syncthreads();

        frag8 a0 = *reinterpret_cast<const frag8*>(&As[wm + lrow][quad * 8]);
        frag8 a1 = *reinterpret_cast<const frag8*>(&As[wm + 16 + lrow][quad * 8]);
        frag8 b0 = *reinterpret_cast<const frag8*>(&Bs[wn + lrow][quad * 8]);
        frag8 b1 = *reinterpret_cast<const frag8*>(&Bs[wn + 16 + lrow][quad * 8]);

        acc[0][0] = __builtin_amdgcn_mfma_f32_16x16x32_bf16(a0, b0, acc[0][0], 0, 0, 0);
        acc[0][1] = __builtin_amdgcn_mfma_f32_16x16x32_bf16(a0, b1, acc[0][1], 0, 0, 0);
        acc[1][0] = __builtin_amdgcn_mfma_f32_16x16x32_bf16(a1, b0, acc[1][0], 0, 0, 0);
        acc[1][1] = __builtin_amdgcn_mfma_f32_16x16x32_bf16(a1, b1, acc[1][1], 0, 0, 0);
        __syncthreads();
    }

    const int bb = m0 >> 10;
    const int tb = m0 & 1023;
    #pragma unroll
    for (int mi = 0; mi < 2; mi++) {
        int t4 = tb + wm + mi * 16 + quad * 4;
        #pragma unroll
        for (int nj = 0; nj < 2; nj++) {
            int col = n0 + wn + nj * 16 + lrow;
            if (col < 512) {
                float4 o = { acc[mi][nj][0], acc[mi][nj][1], acc[mi][nj][2], acc[mi][nj][3] };
                *reinterpret_cast<float4*>(xzuT + ((size_t)(bb * 512 + col)) * 1024 + t4) = o;
            } else {
                int z = col - 512;
                ushort4 o;
                float v0 = acc[mi][nj][0], v1 = acc[mi][nj][1], v2 = acc[mi][nj][2], v3 = acc[mi][nj][3];
                o.x = bf16bits(v0 * sigmoid_f(v0));
                o.y = bf16bits(v1 * sigmoid_f(v1));
                o.z = bf16bits(v2 * sigmoid_f(v2));
                o.w = bf16bits(v3 * sigmoid_f(v3));
                *reinterpret_cast<ushort4*>(szT + ((size_t)(bb * 512 + z)) * 1024 + t4) = o;
            }
        }
    }
}

// ---------------- MFMA GEMM, A from ucT [B=4][K=512][T=1024] fp32 ---------------
__global__ __launch_bounds__(256)
void gemm_at(const float* __restrict__ AT,
             const unsigned short* __restrict__ W,
             float* __restrict__ C,
             int N, int K)
{
    __shared__ __align__(16) unsigned short As[64][40];
    __shared__ __align__(16) unsigned short Bs[64][40];

    const int tid = threadIdx.x;
    const int wid = tid >> 6, lane = tid & 63;
    const int wm = (wid >> 1) * 32, wn = (wid & 1) * 32;
    const int m0 = blockIdx.y * 64;
    const int bb = m0 >> 10;
    const int tb = m0 & 1023;
    const int lrow = lane & 15, quad = lane >> 4;

    const int sm = tid >> 2;
    const int sk = (tid & 3) * 8;

    f32x4 acc[2][2] = {};

    for (int k0 = 0; k0 < K; k0 += 32) {
        #pragma unroll
        for (int p = 0; p < 2; p++) {
            int kk = (tid >> 4) + p * 16;
            int mq = tid & 15;
            float4 v = *reinterpret_cast<const float4*>(AT + ((size_t)(bb * 512 + k0 + kk)) * 1024 + tb + mq * 4);
            As[mq * 4 + 0][kk] = bf16bits(v.x);
            As[mq * 4 + 1][kk] = bf16bits(v.y);
            As[mq * 4 + 2][kk] = bf16bits(v.z);
            As[mq * 4 + 3][kk] = bf16bits(v.w);
        }
        float4 bv = {0.f, 0.f, 0.f, 0.f};
        if (sm < N) bv = *reinterpret_cast<const float4*>(W + (size_t)sm * K + k0 + sk);
        *reinterpret_cast<float4*>(&Bs[sm][sk]) = bv;
        __syncthreads();

        frag8 a0 = *reinterpret_cast<const frag8*>(&As[wm + lrow][quad * 8]);
        frag8 a1 = *reinterpret_cast<const frag8*>(&As[wm + 16 + lrow][quad * 8]);
        frag8 b0 = *reinterpret_cast<const frag8*>(&Bs[wn + lrow][quad * 8]);
        frag8 b1 = *reinterpret_cast<const frag8*>(&Bs[wn + 16 + lrow][quad * 8]);

        acc[0][0] = __builtin_amdgcn_mfma_f32_16x16x32_bf16(a0, b0, acc[0][0], 0, 0, 0);
        acc[0][1] = __builtin_amdgcn_mfma_f32_16x16x32_bf16(a0, b1, acc[0][1], 0, 0, 0);
        acc[1][0] = __builtin_amdgcn_mfma_f32_16x16x32_bf16(a1, b0, acc[1][0], 0, 0, 0);
        acc[1][1] = __builtin_amdgcn_mfma_f32_16x16x32_bf16(a1, b1, acc[1][1], 0, 0, 0);
        __syncthreads();
    }

    #pragma unroll
    for (int mi = 0; mi < 2; mi++) {
        #pragma unroll
        for (int nj = 0; nj < 2; nj++) {
            int col = wn + nj * 16 + lrow;
            if (col >= N) continue;
            #pragma unroll
            for (int r = 0; r < 4; r++) {
                int row = m0 + wm + mi * 16 + quad * 4 + r;
                C[(size_t)row * N + col] = acc[mi][nj][r];
            }
        }
    }
}

// ---------------- full-row GEMM (N=256), 512 threads / 8 waves ------------------
// wave w owns cols [w*32, w*32+32). Fused: bias, res, LN1(+gelu), gelu, outF,
// L2-norm atomic, LN2->outB / outB, and optional cls GEMM (K=256 -> 128 logits).
__global__ __launch_bounds__(512)
void rowgemm(const unsigned short* __restrict__ A,
             const unsigned short* __restrict__ W,
             const float* __restrict__ bias,
             const float* res,
             const float* g1, const float* b1, int gelu1,
             const float* g2, const float* b2,
             float* outF, unsigned short* outB, float* l2out,
             const unsigned short* clsW, const float* clsB, float* clsOut,
             int K)
{
    __shared__ __align__(16) unsigned short As[16][40];
    __shared__ __align__(16) unsigned short Bs[256][40];
    __shared__ float red[8][16][2];
    __shared__ float sq[16];
    __shared__ __align__(16) unsigned short hb[16][264];

    const int tid = threadIdx.x;
    const int w = tid >> 6, lane = tid & 63;
    const int lrow = lane & 15, quad = lane >> 4;
    const int m0 = blockIdx.x * 16;

    f32x4 acc[2] = {};

    for (int k0 = 0; k0 < K; k0 += 32) {
        if (tid < 64) {
            float4 av = *reinterpret_cast<const float4*>(A + (size_t)(m0 + (tid >> 2)) * K + k0 + (tid & 3) * 8);
            *reinterpret_cast<float4*>(&As[tid >> 2][(tid & 3) * 8]) = av;
        }
        #pragma unroll
        for (int i = 0; i < 2; i++) {
            int n = (tid >> 2) + i * 128;
            float4 bv = *reinterpret_cast<const float4*>(W + (size_t)n * K + k0 + (tid & 3) * 8);
            *reinterpret_cast<float4*>(&Bs[n][(tid & 3) * 8]) = bv;
        }
        __syncthreads();
        frag8 a = *reinterpret_cast<const frag8*>(&As[lrow][quad * 8]);
        #pragma unroll
        for (int nj = 0; nj < 2; nj++) {
            frag8 b = *reinterpret_cast<const frag8*>(&Bs[w * 32 + nj * 16 + lrow][quad * 8]);
            acc[nj] = __builtin_amdgcn_mfma_f32_16x16x32_bf16(a, b, acc[nj], 0, 0, 0);
        }
        __syncthreads();
    }

    float v[2][4];
    #pragma unroll
    for (int nj = 0; nj < 2; nj++) {
        int col = w * 32 + nj * 16 + lrow;
        #pragma unroll
        for (int r = 0; r < 4; r++) {
            int row = m0 + quad * 4 + r;
            float t = acc[nj][r];
            if (bias) t += bias[col];
            if (res) t += res[(size_t)row * 256 + col];
            v[nj][r] = t;
        }
    }

    if (g1) {
        #pragma unroll
        for (int r = 0; r < 4; r++) {
            float s1 = v[0][r] + v[1][r];
            float s2 = v[0][r]*v[0][r] + v[1][r]*v[1][r];
            s1 = row_sum16(s1); s2 = row_sum16(s2);
            if (lrow == 0) { red[w][quad * 4 + r][0] = s1; red[w][quad * 4 + r][1] = s2; }
        }
        __syncthreads();
        #pragma unroll
        for (int r = 0; r < 4; r++) {
            int rr = quad * 4 + r;
            float t1 = 0.f, t2 = 0.f;
            #pragma unroll
            for (int ww = 0; ww < 8; ww++) { t1 += red[ww][rr][0]; t2 += red[ww][rr][1]; }
            float mu = t1 * (1.0f / 256.0f);
            float var = t2 * (1.0f / 256.0f) - mu * mu;
            float rstd = rsqrtf(var + 1e-5f);
            #pragma unroll
            for (int nj = 0; nj < 2; nj++) {
                int col = w * 32 + nj * 16 + lrow;
                float t = (v[nj][r] - mu) * rstd * g1[col] + b1[col];
                if (gelu1) t = gelu_exact(t);
                v[nj][r] = t;
            }
        }
        __syncthreads();
    } else if (gelu1) {
        #pragma unroll
        for (int nj = 0; nj < 2; nj++)
            #pragma unroll
            for (int r = 0; r < 4; r++)
                v[nj][r] = gelu_exact(v[nj][r]);
    }

    if (outF) {
        #pragma unroll
        for (int nj = 0; nj < 2; nj++) {
            int col = w * 32 + nj * 16 + lrow;
            #pragma unroll
            for (int r = 0; r < 4; r++)
                outF[(size_t)(m0 + quad * 4 + r) * 256 + col] = v[nj][r];
        }
    }

    if (l2out) {
        #pragma unroll
        for (int r = 0; r < 4; r++) {
            float s2 = v[0][r]*v[0][r] + v[1][r]*v[1][r];
            s2 = row_sum16(s2);
            if (lrow == 0) red[w][quad * 4 + r][0] = s2;
        }
        __syncthreads();
        if (tid < 16) {
            float t = 0.f;
            #pragma unroll
            for (int ww = 0; ww < 8; ww++) t += red[ww][tid][0];
            sq[tid] = sqrtf(t);
        }
        __syncthreads();
        if (tid == 0) {
            float a = 0.f;
            #pragma unroll
            for (int i = 0; i < 16; i++) a += sq[i];
            atomicAdd(l2out, a * (0.01f / 4096.0f));
        }
    }

    if (g2) {
        __syncthreads();
        #pragma unroll
        for (int r = 0; r < 4; r++) {
            float s1 = v[0][r] + v[1][r];
            float s2 = v[0][r]*v[0][r] + v[1][r]*v[1][r];
            s1 = row_sum16(s1); s2 = row_sum16(s2);
            if (lrow == 0) { red[w][quad * 4 + r][0] = s1; red[w][quad * 4 + r][1] = s2; }
        }
        __syncthreads();
        #pragma unroll
        for (int r = 0; r < 4; r++) {
            int rr = quad * 4 + r;
            float t1 = 0.f, t2 = 0.f;
            #pragma unroll
            for (int ww = 0; ww < 8; ww++) { t1 += red[ww][rr][0]; t2 += red[ww][rr][1]; }
            float mu = t1 * (1.0f / 256.0f);
            float var = t2 * (1.0f / 256.0f) - mu * mu;
            float rstd = rsqrtf(var + 1e-5f);
            #pragma unroll
            for (int nj = 0; nj < 2; nj++) {
                int col = w * 32 + nj * 16 + lrow;
                outB[(size_t)(m0 + rr) * 256 + col] = bf16bits((v[nj][r] - mu) * rstd * g2[col] + b2[col]);
            }
        }
    } else if (outB) {
        #pragma unroll
        for (int nj = 0; nj < 2; nj++) {
            int col = w * 32 + nj * 16 + lrow;
            #pragma unroll
            for (int r = 0; r < 4; r++)
                outB[(size_t)(m0 + quad * 4 + r) * 256 + col] = bf16bits(v[nj][r]);
        }
    }

    // ---- fused cls GEMM: logits(16 x 128) = v(16 x 256) @ clsW(128 x 256)^T ----
    if (clsW) {
        #pragma unroll
        for (int nj = 0; nj < 2; nj++) {
            int col = w * 32 + nj * 16 + lrow;
            #pragma unroll
            for (int r = 0; r < 4; r++)
                hb[quad * 4 + r][col] = bf16bits(v[nj][r]);
        }
        __syncthreads();
        f32x4 cacc = {};
        #pragma unroll
        for (int k0 = 0; k0 < 256; k0 += 32) {
            frag8 a = *reinterpret_cast<const frag8*>(&hb[lrow][k0 + quad * 8]);
            frag8 b = *reinterpret_cast<const frag8*>(clsW + (size_t)(w * 16 + lrow) * 256 + k0 + quad * 8);
            cacc = __builtin_amdgcn_mfma_f32_16x16x32_bf16(a, b, cacc, 0, 0, 0);
        }
        int col = w * 16 + lrow;
        float cb = clsB[col];
        #pragma unroll
        for (int r = 0; r < 4; r++)
            clsOut[(size_t)(m0 + quad * 4 + r) * 128 + col] = cacc[r] + cb;
    }
}

// ---------------- causal conv4 + bias + SiLU on transposed u ---------------------
__global__ __launch_bounds__(256)
void conv_T(const float* __restrict__ xzuT, const float* __restrict__ cw,
            const float* __restrict__ cb, float* __restrict__ ucT)
{
    __shared__ float xs[64][68];
    const int bx = blockIdx.x;
    const int b = bx >> 7;
    const int dt_ = (bx >> 4) & 7;
    const int tt = bx & 15;
    const int tid = threadIdx.x;
    const int d0 = dt_ * 64, t0 = tt * 64;

    {
        const int dd = tid >> 2;
        const int c0_ = (tid & 3) * 17;
        const float* src = xzuT + ((size_t)(b * 512 + d0 + dd)) * 1024 + t0 - 3;
        #pragma unroll
        for (int k = 0; k < 17; k++) {
            int tc = c0_ + k;
            if (tc < 67) {
                int tg = t0 - 3 + tc;
                xs[dd][tc] = (tg >= 0) ? src[tc] : 0.0f;
            }
        }
    }
    __syncthreads();

    const int tl = tid & 63, dgrp = tid >> 6;
    #pragma unroll 4
    for (int dp = 0; dp < 16; dp++) {
        int dd = dp * 4 + dgrp;
        int d = d0 + dd;
        float c0 = cw[d * 4 + 0], c1 = cw[d * 4 + 1], c2 = cw[d * 4 + 2], c3 = cw[d * 4 + 3];
        float acc = cb[d] + xs[dd][tl] * c0 + xs[dd][tl + 1] * c1 + xs[dd][tl + 2] * c2 + xs[dd][tl + 3] * c3;
        ucT[((size_t)(b * 512 + d)) * 1024 + t0 + tl] = acc * sigmoid_f(acc);
    }
}

// ---------------- dt proj + softplus -> dltT ; fused B/C transpose --------------
__global__ __launch_bounds__(256)
void dtbc(const float* __restrict__ xdbc, const float* __restrict__ dtw,
          const float* __restrict__ dtb, float* __restrict__ dltT,
          float* __restrict__ BT, float* __restrict__ CT)
{
    __shared__ float xd[64][17];
    __shared__ float wS[64][16];
    __shared__ float bS[64];
    const int bx = blockIdx.x;
    const int b = bx >> 7;
    const int tt = (bx >> 3) & 15;
    const int dg = bx & 7;
    const int tid = threadIdx.x;
    const int t0 = tt * 64, d0 = dg * 64;

    for (int i = tid; i < 64 * 16; i += 256) {
        int t = i >> 4, k = i & 15;
        xd[t][k] = xdbc[((size_t)(b * 1024 + t0 + t)) * 48 + k];
    }
    for (int i = tid; i < 64 * 16; i += 256) {
        int dl = i >> 4, k = i & 15;
        wS[dl][k] = dtw[(d0 + dl) * 16 + k];
    }
    if (tid < 64) bS[tid] = dtb[d0 + tid];
    __syncthreads();

    const int tl = tid & 63, w = tid >> 6;
    #pragma unroll 4
    for (int di = 0; di < 16; di++) {
        int dl = w * 16 + di;
        float acc = bS[dl];
        #pragma unroll
        for (int k = 0; k < 16; k++) acc += xd[tl][k] * wS[dl][k];
        dltT[((size_t)(b * 512 + d0 + dl)) * 1024 + t0 + tl] = softplus_f(acc);
    }

    {
        int c = tid >> 6;
        int t = tid & 63;
        int col = dg * 4 + c;
        float v = xdbc[((size_t)(b * 1024 + t0 + t)) * 48 + 16 + col];
        if (col < 16) BT[((size_t)(b * 16 + col)) * 1024 + t0 + t] = v;
        else          CT[((size_t)(b * 16 + col - 16)) * 1024 + t0 + t] = v;
    }
}

// ---------------- chunked selective scan (1 barrier, decentralized combine) -----
__global__ __launch_bounds__(1024)
void scan_chunked(const float* __restrict__ dltT, const float* __restrict__ ucT,
                  const float* __restrict__ BT, const float* __restrict__ CT,
                  const unsigned short* __restrict__ szT,
                  const float* __restrict__ Ac,
                  const float* __restrict__ Dp,
                  unsigned short* __restrict__ y)
{
    __shared__ float aprod_s[16][64];
    __shared__ float sfin_s[16][64];
    __shared__ float sin_w[16][64];
    __shared__ __align__(16) float ylocal[16][64][4];

    const int j = blockIdx.x;
    const int bid = (j & 7) * 64 + (j >> 3);     // XCD swizzle
    const int b = bid >> 7;
    const int d0 = (bid & 127) * 4;
    const int w = threadIdx.x >> 6;
    const int lane = threadIdx.x & 63;
    const int dsub = lane >> 4, s = lane & 15;
    const int d = d0 + dsub;

    const float Acoef = Ac[d * 16 + s];

    const float4* dp = reinterpret_cast<const float4*>(dltT + ((size_t)(b * 512 + d)) * 1024 + w * 64);
    const float4* up = reinterpret_cast<const float4*>(ucT  + ((size_t)(b * 512 + d)) * 1024 + w * 64);
    const float4* Bp = reinterpret_cast<const float4*>(BT + ((size_t)(b * 16 + s)) * 1024 + w * 64);
    const float4* Cp = reinterpret_cast<const float4*>(CT + ((size_t)(b * 16 + s)) * 1024 + w * 64);

    // ---- Phase A: local scan with cumprod (q+1 prefetch) ----
    float st = 0.0f, ap = 1.0f;
    float4 dt4 = dp[0], ut4 = up[0], B4 = Bp[0], C4 = Cp[0];
    #pragma unroll
    for (int q = 0; q < 16; q++) {
        float4 ndt, nut, nB, nC;
        if (q < 15) { ndt = dp[q + 1]; nut = up[q + 1]; nB = Bp[q + 1]; nC = Cp[q + 1]; }
        const float* dtp = (const float*)&dt4;
        const float* utp = (const float*)&ut4;
        const float* Btp = (const float*)&B4;
        const float* Ctp = (const float*)&C4;
        #pragma unroll
        for (int jj = 0; jj < 4; jj++) {
            float dA = __expf(dtp[jj] * Acoef);
            st = st * dA + dtp[jj] * utp[jj] * Btp[jj];
            ap *= dA;
            float part = row_sum16(st * Ctp[jj]);
            if (s == 0) ylocal[w][q * 4 + jj][dsub] = part;
        }
        dt4 = ndt; ut4 = nut; B4 = nB; C4 = nC;
    }
    aprod_s[w][lane] = ap;
    sfin_s[w][lane] = st;
    __syncthreads();                                 // the only barrier

    // ---- decentralized combine ----
    {
        float pre = 0.0f;
        #pragma unroll
        for (int c = 0; c < 15; c++) {
            float apc = aprod_s[c][lane];
            float sfc = sfin_s[c][lane];
            float cand = sfc + apc * pre;
            pre = (c < w) ? cand : pre;
        }
        sin_w[w][lane] = pre;
    }

    // ---- Phase C: lane = t; correction via prefix sums + epilogue ----
    const int t = w * 64 + lane;
    float cums[4];
    #pragma unroll
    for (int dd = 0; dd < 4; dd++)
        cums[dd] = dltT[((size_t)(b * 512 + d0 + dd)) * 1024 + t];
    #pragma unroll
    for (int dd = 0; dd < 4; dd++)
        cums[dd] = prefix_sum64(cums[dd]);

    float4 yl = *reinterpret_cast<const float4*>(&ylocal[w][lane][0]);
    float acc[4] = { yl.x, yl.y, yl.z, yl.w };

    #pragma unroll
    for (int sq = 0; sq < 4; sq++) {
        float Cs[4];
        #pragma unroll
        for (int jj = 0; jj < 4; jj++)
            Cs[jj] = CT[((size_t)(b * 16 + sq * 4 + jj)) * 1024 + t];
        #pragma unroll
        for (int dd = 0; dd < 4; dd++) {
            float4 sin4 = *reinterpret_cast<const float4*>(&sin_w[w][dd * 16 + sq * 4]);
            const float* sp = (const float*)&sin4;
            #pragma unroll
            for (int jj = 0; jj < 4; jj++) {
                float ac = Ac[(d0 + dd) * 16 + sq * 4 + jj];
                acc[dd] += sp[jj] * Cs[jj] * __expf(ac * cums[dd]);
            }
        }
    }

    const size_t row = (size_t)b * 1024 + t;
    #pragma unroll
    for (int dd = 0; dd < 4; dd++) {
        float ut = ucT[((size_t)(b * 512 + d0 + dd)) * 1024 + t];
        float sz = bf2f(szT[((size_t)(b * 512 + d0 + dd)) * 1024 + t]);
        float yv = acc[dd] + ut * Dp[d0 + dd];
        y[row * 512 + d0 + dd] = bf16bits(yv * sz);
    }
}

// ---------------- launcher ----------------
extern "C" void kernel_launch(void* const* d_in, const int* in_sizes, int n_in,
                              void* d_out, int out_size, void* d_ws, size_t ws_size,
                              hipStream_t stream)
{
    const float* x      = (const float*)d_in[0];
    const float* in_b   = (const float*)d_in[2];
    const float* ln_g   = (const float*)d_in[3];
    const float* ln_b   = (const float*)d_in[4];
    const float* blk_ng  = (const float*)d_in[5];
    const float* blk_nb  = (const float*)d_in[6];
    const float* blk_cw  = (const float*)d_in[8];
    const float* blk_cb  = (const float*)d_in[9];
    const float* blk_dtw = (const float*)d_in[11];
    const float* blk_dtb = (const float*)d_in[12];
    const float* blk_Alog= (const float*)d_in[13];
    const float* blk_D   = (const float*)d_in[14];
    const float* op_b   = (const float*)d_in[17];
    const float* cls_b  = (const float*)d_in[19];
    float* out = (float*)d_out;

    const int BL = 4096;
    float* ws = (float*)d_ws;
    float* h0   = ws;                         // 1,048,576
    float* xzuT = h0 + 1048576;               // 2,097,152  [b][d][t] fp32 (u pre-conv)
    float* ucT  = xzuT + 2097152;             // 2,097,152  [b][d][t]
    float* xdbc = ucT + 2097152;              //   196,608
    float* dltT = xdbc + 196608;              // 2,097,152  [b][d][t]
    float* BT   = dltT + 2097152;             //    65,536  [b][s][t]
    float* CT   = BT + 65536;                 //    65,536  [b][s][t]
    float* Ac   = CT + 65536;                 //    16,384
    unsigned short* szT = (unsigned short*)(Ac + 16384);  // 2,097,152 bf16 [b][d][t]
    unsigned short* wb  = szT + 2097152;      // 1,130,496
    unsigned short* hnb = wb + 1130496;       // 1,048,576
    unsigned short* ybb = hnb + 1048576;      // 2,097,152
    unsigned short* xb  = (unsigned short*)dltT;  // x bf16 (dead before dltT written)
    unsigned short* h0b = hnb;
    unsigned short* in_wb  = wb;
    unsigned short* ipw_b  = wb + 196608;
    unsigned short* xpw_b  = wb + 720896;
    unsigned short* opw_b  = wb + 770048;
    unsigned short* op_wb  = wb + 1032192;
    unsigned short* cls_wb = wb + 1097728;

    CvtArgs ca;
    ca.src[0] = x;                  ca.dst[0] = xb;     ca.n4[0] = 3145728 / 4;
    ca.src[1] = (const float*)d_in[1];  ca.dst[1] = in_wb;  ca.n4[1] = 196608 / 4;
    ca.src[2] = (const float*)d_in[7];  ca.dst[2] = ipw_b;  ca.n4[2] = 524288 / 4;
    ca.src[3] = (const float*)d_in[10]; ca.dst[3] = xpw_b;  ca.n4[3] = 49152 / 4;
    ca.src[4] = (const float*)d_in[15]; ca.dst[4] = opw_b;  ca.n4[4] = 262144 / 4;
    ca.src[5] = (const float*)d_in[16]; ca.dst[5] = op_wb;  ca.n4[5] = 65536 / 4;
    ca.src[6] = (const float*)d_in[18]; ca.dst[6] = cls_wb; ca.n4[6] = 32768 / 4;
    int total4 = (3145728 + 1130496) / 4;
    int totalg = total4 + 16384;
    cvt_all<<<(totalg + 255) / 256, 256, 0, stream>>>(ca, total4, blk_Alog, Ac,
                                                      out + (size_t)BL * 128);

    // in_proj + bias + LN + GELU -> h0 (fp32), + LN(layer0) -> hnb (bf16)
    rowgemm<<<256, 512, 0, stream>>>(xb, in_wb, in_b, nullptr,
                                     ln_g, ln_b, 1,
                                     blk_ng, blk_nb,
                                     h0, hnb, nullptr,
                                     nullptr, nullptr, nullptr, 768);

    for (int l = 0; l < 2; l++) {
        const float* cw   = blk_cw  + (size_t)l * 512 * 4;
        const float* cb   = blk_cb  + l * 512;
        const float* dtw  = blk_dtw + (size_t)l * 512 * 16;
        const float* dtb  = blk_dtb + l * 512;
        const float* Dl   = blk_D   + l * 512;
        const unsigned short* ipwl = ipw_b + (size_t)l * 262144;
        const unsigned short* xpwl = xpw_b + (size_t)l * 24576;
        const unsigned short* opwl = opw_b + (size_t)l * 131072;

        // ipw GEMM: u -> xzuT fp32 [b][d][t]; z -> silu(z) bf16 szT [b][d][t]
        gemm_ipw<<<dim3(16, 64), 256, 0, stream>>>(hnb, ipwl, xzuT, szT);
        // ucT = silu(conv(u)+cb) [b][d][t]
        conv_T<<<512, 256, 0, stream>>>(xzuT, cw, cb, ucT);
        // xdbc = u @ xpw.T  (N=48, K=512), A read from ucT [b][k][t]
        gemm_at<<<dim3(1, 64), 256, 0, stream>>>(ucT, xpwl, xdbc, 48, 512);
        // dltT (softplus) + fused BT/CT transpose
        dtbc<<<512, 256, 0, stream>>>(xdbc, dtw, dtb, dltT, BT, CT);
        // scan -> ybb
        scan_chunked<<<512, 1024, 0, stream>>>(dltT, ucT, BT, CT, szT,
                                               Ac + (size_t)l * 8192, Dl, ybb);
        // h0 += ybb @ opw.T; layer0: +LN(layer1)->hnb; layer1: ->h0b bf16 only
        if (l == 0)
            rowgemm<<<256, 512, 0, stream>>>(ybb, opwl, nullptr, h0,
                                             nullptr, nullptr, 0,
                                             blk_ng + 256, blk_nb + 256,
                                             h0, hnb, nullptr,
                                             nullptr, nullptr, nullptr, 512);
        else
            rowgemm<<<256, 512, 0, stream>>>(ybb, opwl, nullptr, h0,
                                             nullptr, nullptr, 0,
                                             nullptr, nullptr,
                                             nullptr, h0b, nullptr,
                                             nullptr, nullptr, nullptr, 512);
    }

    // final: h2 = gelu(h0b @ op_w.T + op_b); fused L2 scalar + cls GEMM -> out
    rowgemm<<<256, 512, 0, stream>>>(h0b, op_wb, op_b, nullptr,
                                     nullptr, nullptr, 1,
                                     nullptr, nullptr,
                                     nullptr, nullptr, out + (size_t)BL * 128,
                                     cls_wb, cls_b, out, 256);
}

// Round 13
// 325.205 us; speedup vs baseline: 1.2862x; 1.0749x over previous
//
#include <hip/hip_runtime.h>
#include <hip/hip_bf16.h>
#include <math.h>

typedef __attribute__((ext_vector_type(8))) short frag8;   // 8 bf16 (4 VGPRs)
typedef __attribute__((ext_vector_type(4))) float f32x4;

// ---------------- device helpers ----------------
__device__ __forceinline__ float gelu_exact(float x) {
    return 0.5f * x * (1.0f + erff(x * 0.70710678118654752f));
}
__device__ __forceinline__ float softplus_f(float x) {
    return (x > 20.0f) ? x : log1pf(expf(x));
}
__device__ __forceinline__ float sigmoid_f(float x) {
    return 1.0f / (1.0f + __expf(-x));
}
__device__ __forceinline__ unsigned short bf16bits(float x) {
    __hip_bfloat16 h = __float2bfloat16(x);
    return *(unsigned short*)&h;
}
__device__ __forceinline__ float bf2f(unsigned short u) {
    unsigned int v = ((unsigned int)u) << 16;
    return __builtin_bit_cast(float, v);
}
// sum over the 16 lanes of each DPP row-of-16 — VALU-pipe only
__device__ __forceinline__ float row_sum16(float x) {
    int t;
    t = __builtin_amdgcn_update_dpp(0, __builtin_bit_cast(int, x), 0x128, 0xf, 0xf, true); // row_ror:8
    x += __builtin_bit_cast(float, t);
    t = __builtin_amdgcn_update_dpp(0, __builtin_bit_cast(int, x), 0x124, 0xf, 0xf, true); // row_ror:4
    x += __builtin_bit_cast(float, t);
    t = __builtin_amdgcn_update_dpp(0, __builtin_bit_cast(int, x), 0x122, 0xf, 0xf, true); // row_ror:2
    x += __builtin_bit_cast(float, t);
    t = __builtin_amdgcn_update_dpp(0, __builtin_bit_cast(int, x), 0x121, 0xf, 0xf, true); // row_ror:1
    x += __builtin_bit_cast(float, t);
    return x;
}
// inclusive prefix sum over the full 64-lane wave (DPP, VALU-pipe only)
__device__ __forceinline__ float prefix_sum64(float x) {
    int t;
    t = __builtin_amdgcn_update_dpp(0, __builtin_bit_cast(int, x), 0x111, 0xf, 0xf, true); // row_shr:1
    x += __builtin_bit_cast(float, t);
    t = __builtin_amdgcn_update_dpp(0, __builtin_bit_cast(int, x), 0x112, 0xf, 0xf, true); // row_shr:2
    x += __builtin_bit_cast(float, t);
    t = __builtin_amdgcn_update_dpp(0, __builtin_bit_cast(int, x), 0x114, 0xf, 0xf, true); // row_shr:4
    x += __builtin_bit_cast(float, t);
    t = __builtin_amdgcn_update_dpp(0, __builtin_bit_cast(int, x), 0x118, 0xf, 0xf, true); // row_shr:8
    x += __builtin_bit_cast(float, t);
    t = __builtin_amdgcn_update_dpp(0, __builtin_bit_cast(int, x), 0x142, 0xa, 0xf, true); // row_bcast:15
    x += __builtin_bit_cast(float, t);
    t = __builtin_amdgcn_update_dpp(0, __builtin_bit_cast(int, x), 0x143, 0xc, 0xf, true); // row_bcast:31
    x += __builtin_bit_cast(float, t);
    return x;
}

// ---------------- fused fp32 -> bf16 conversion + Acoef setup + l2 zero --------
struct CvtArgs {
    const float* src[7];
    unsigned short* dst[7];
    int n4[7];
};
__global__ __launch_bounds__(256)
void cvt_all(CvtArgs a, int total4, const float* __restrict__ Alog,
             float* __restrict__ Ac, float* l2)
{
    int i = blockIdx.x * 256 + threadIdx.x;
    if (i >= total4) {
        int j = i - total4;
        if (j < 16384) Ac[j] = -__expf(Alog[j]);
        if (j == 0) *l2 = 0.0f;
        return;
    }
    int seg = 0;
    while (i >= a.n4[seg]) { i -= a.n4[seg]; seg++; }
    float4 v = reinterpret_cast<const float4*>(a.src[seg])[i];
    ushort4 o;
    o.x = bf16bits(v.x); o.y = bf16bits(v.y); o.z = bf16bits(v.z); o.w = bf16bits(v.w);
    reinterpret_cast<ushort4*>(a.dst[seg])[i] = o;
}

// ---------------- ipw GEMM (N=1024, K=256): u-half -> xzuT fp32 [b][d][t],
// ---------------- z-half -> silu(z) bf16 szT [b][d][t] ----------------
__global__ __launch_bounds__(256)
void gemm_ipw(const unsigned short* __restrict__ A,
              const unsigned short* __restrict__ W,
              float* __restrict__ xzuT,
              unsigned short* __restrict__ szT)
{
    __shared__ __align__(16) unsigned short As[64][40];
    __shared__ __align__(16) unsigned short Bs[64][40];

    const int tid = threadIdx.x;
    const int wid = tid >> 6, lane = tid & 63;
    const int wm = (wid >> 1) * 32, wn = (wid & 1) * 32;
    const int m0 = blockIdx.y * 64, n0 = blockIdx.x * 64;
    const int lrow = lane & 15, quad = lane >> 4;
    const int K = 256;

    const int sm = tid >> 2;
    const int sk = (tid & 3) * 8;

    f32x4 acc[2][2] = {};

    for (int k0 = 0; k0 < K; k0 += 32) {
        float4 av = *reinterpret_cast<const float4*>(A + (size_t)(m0 + sm) * K + k0 + sk);
        *reinterpret_cast<float4*>(&As[sm][sk]) = av;
        float4 bv = *reinterpret_cast<const float4*>(W + (size_t)(n0 + sm) * K + k0 + sk);
        *reinterpret_cast<float4*>(&Bs[sm][sk]) = bv;
        __syncthreads();

        frag8 a0 = *reinterpret_cast<const frag8*>(&As[wm + lrow][quad * 8]);
        frag8 a1 = *reinterpret_cast<const frag8*>(&As[wm + 16 + lrow][quad * 8]);
        frag8 b0 = *reinterpret_cast<const frag8*>(&Bs[wn + lrow][quad * 8]);
        frag8 b1 = *reinterpret_cast<const frag8*>(&Bs[wn + 16 + lrow][quad * 8]);

        acc[0][0] = __builtin_amdgcn_mfma_f32_16x16x32_bf16(a0, b0, acc[0][0], 0, 0, 0);
        acc[0][1] = __builtin_amdgcn_mfma_f32_16x16x32_bf16(a0, b1, acc[0][1], 0, 0, 0);
        acc[1][0] = __builtin_amdgcn_mfma_f32_16x16x32_bf16(a1, b0, acc[1][0], 0, 0, 0);
        acc[1][1] = __builtin_amdgcn_mfma_f32_16x16x32_bf16(a1, b1, acc[1][1], 0, 0, 0);
        __syncthreads();
    }

    const int bb = m0 >> 10;
    const int tb = m0 & 1023;
    #pragma unroll
    for (int mi = 0; mi < 2; mi++) {
        int t4 = tb + wm + mi * 16 + quad * 4;
        #pragma unroll
        for (int nj = 0; nj < 2; nj++) {
            int col = n0 + wn + nj * 16 + lrow;
            if (col < 512) {
                float4 o = { acc[mi][nj][0], acc[mi][nj][1], acc[mi][nj][2], acc[mi][nj][3] };
                *reinterpret_cast<float4*>(xzuT + ((size_t)(bb * 512 + col)) * 1024 + t4) = o;
            } else {
                int z = col - 512;
                ushort4 o;
                float v0 = acc[mi][nj][0], v1 = acc[mi][nj][1], v2 = acc[mi][nj][2], v3 = acc[mi][nj][3];
                o.x = bf16bits(v0 * sigmoid_f(v0));
                o.y = bf16bits(v1 * sigmoid_f(v1));
                o.z = bf16bits(v2 * sigmoid_f(v2));
                o.w = bf16bits(v3 * sigmoid_f(v3));
                *reinterpret_cast<ushort4*>(szT + ((size_t)(bb * 512 + z)) * 1024 + t4) = o;
            }
        }
    }
}

// ---------------- conv4+SiLU fused into xpw projection, K-split x4 --------------
// reads xzuT [b][d][t] (pre-conv u), writes ucT [b][d][t] (post-conv, fp32) and
// partial products xdbcp[kc] (4096 x 48 fp32): chunk 0 -> xp0, chunks 1-3 -> xp123.
__global__ __launch_bounds__(256)
void gemm_cat(const float* __restrict__ xzuT,
              const unsigned short* __restrict__ W,     // xpw: 48 x 512 bf16
              const float* __restrict__ cw, const float* __restrict__ cb,
              float* __restrict__ ucT,
              float* __restrict__ xp0, float* __restrict__ xp123)
{
    __shared__ __align__(16) unsigned short As[64][40];
    __shared__ __align__(16) unsigned short Bs[64][40];

    const int tid = threadIdx.x;
    const int wid = tid >> 6, lane = tid & 63;
    const int wm = (wid >> 1) * 32, wn = (wid & 1) * 32;
    const int kc = blockIdx.x;            // 0..3 (128-d chunk)
    const int m0 = blockIdx.y * 64;
    const int bb = m0 >> 10;
    const int tb = m0 & 1023;
    const int lrow = lane & 15, quad = lane >> 4;
    const int N = 48;

    const int sm = tid >> 2;
    const int sk = (tid & 3) * 8;

    f32x4 acc[2][2] = {};

    for (int k0 = 0; k0 < 128; k0 += 32) {
        #pragma unroll
        for (int p = 0; p < 2; p++) {
            int kk = (tid >> 4) + p * 16;          // 0..31 within k-tile
            int k  = kc * 128 + k0 + kk;           // global d index
            int mq = tid & 15;
            int tg = tb + mq * 4;                  // global t of cur.x
            const float* rowp = xzuT + ((size_t)(bb * 512 + k)) * 1024;
            float4 cur = *reinterpret_cast<const float4*>(rowp + tg);
            float4 prev = {0.f, 0.f, 0.f, 0.f};
            if (tg != 0) prev = *reinterpret_cast<const float4*>(rowp + tg - 4);
            float4 cv = *reinterpret_cast<const float4*>(cw + k * 4);
            float cbv = cb[k];
            float o0 = cbv + cv.x*prev.y + cv.y*prev.z + cv.z*prev.w + cv.w*cur.x;
            float o1 = cbv + cv.x*prev.z + cv.y*prev.w + cv.z*cur.x  + cv.w*cur.y;
            float o2 = cbv + cv.x*prev.w + cv.y*cur.x  + cv.z*cur.y  + cv.w*cur.z;
            float o3 = cbv + cv.x*cur.x  + cv.y*cur.y  + cv.z*cur.z  + cv.w*cur.w;
            o0 *= sigmoid_f(o0); o1 *= sigmoid_f(o1);
            o2 *= sigmoid_f(o2); o3 *= sigmoid_f(o3);
            float4 uo = { o0, o1, o2, o3 };
            *reinterpret_cast<float4*>(ucT + ((size_t)(bb * 512 + k)) * 1024 + tg) = uo;
            As[mq * 4 + 0][kk] = bf16bits(o0);
            As[mq * 4 + 1][kk] = bf16bits(o1);
            As[mq * 4 + 2][kk] = bf16bits(o2);
            As[mq * 4 + 3][kk] = bf16bits(o3);
        }
        float4 bv = {0.f, 0.f, 0.f, 0.f};
        if (sm < N) bv = *reinterpret_cast<const float4*>(W + (size_t)sm * 512 + kc * 128 + k0 + sk);
        *reinterpret_cast<float4*>(&Bs[sm][sk]) = bv;
        __syncthreads();

        frag8 a0 = *reinterpret_cast<const frag8*>(&As[wm + lrow][quad * 8]);
        frag8 a1 = *reinterpret_cast<const frag8*>(&As[wm + 16 + lrow][quad * 8]);
        frag8 b0 = *reinterpret_cast<const frag8*>(&Bs[wn + lrow][quad * 8]);
        frag8 b1 = *reinterpret_cast<const frag8*>(&Bs[wn + 16 + lrow][quad * 8]);

        acc[0][0] = __builtin_amdgcn_mfma_f32_16x16x32_bf16(a0, b0, acc[0][0], 0, 0, 0);
        acc[0][1] = __builtin_amdgcn_mfma_f32_16x16x32_bf16(a0, b1, acc[0][1], 0, 0, 0);
        acc[1][0] = __builtin_amdgcn_mfma_f32_16x16x32_bf16(a1, b0, acc[1][0], 0, 0, 0);
        acc[1][1] = __builtin_amdgcn_mfma_f32_16x16x32_bf16(a1, b1, acc[1][1], 0, 0, 0);
        __syncthreads();
    }

    float* C = (kc == 0) ? xp0 : (xp123 + (size_t)(kc - 1) * 4096 * 48);
    #pragma unroll
    for (int mi = 0; mi < 2; mi++) {
        #pragma unroll
        for (int nj = 0; nj < 2; nj++) {
            int col = wn + nj * 16 + lrow;
            if (col >= N) continue;
            #pragma unroll
            for (int r = 0; r < 4; r++) {
                int row = m0 + wm + mi * 16 + quad * 4 + r;
                C[(size_t)row * N + col] = acc[mi][nj][r];
            }
        }
    }
}

// ---------------- full-row GEMM (N=256), 512 threads / 8 waves ------------------
__global__ __launch_bounds__(512)
void rowgemm(const unsigned short* __restrict__ A,
             const unsigned short* __restrict__ W,
             const float* __restrict__ bias,
             const float* res,
             const float* g1, const float* b1, int gelu1,
             const float* g2, const float* b2,
             float* outF, unsigned short* outB, float* l2out,
             const unsigned short* clsW, const float* clsB, float* clsOut,
             int K)
{
    __shared__ __align__(16) unsigned short As[16][40];
    __shared__ __align__(16) unsigned short Bs[256][40];
    __shared__ float red[8][16][2];
    __shared__ float sq[16];
    __shared__ __align__(16) unsigned short hb[16][264];

    const int tid = threadIdx.x;
    const int w = tid >> 6, lane = tid & 63;
    const int lrow = lane & 15, quad = lane >> 4;
    const int m0 = blockIdx.x * 16;

    f32x4 acc[2] = {};

    for (int k0 = 0; k0 < K; k0 += 32) {
        if (tid < 64) {
            float4 av = *reinterpret_cast<const float4*>(A + (size_t)(m0 + (tid >> 2)) * K + k0 + (tid & 3) * 8);
            *reinterpret_cast<float4*>(&As[tid >> 2][(tid & 3) * 8]) = av;
        }
        #pragma unroll
        for (int i = 0; i < 2; i++) {
            int n = (tid >> 2) + i * 128;
            float4 bv = *reinterpret_cast<const float4*>(W + (size_t)n * K + k0 + (tid & 3) * 8);
            *reinterpret_cast<float4*>(&Bs[n][(tid & 3) * 8]) = bv;
        }
        __syncthreads();
        frag8 a = *reinterpret_cast<const frag8*>(&As[lrow][quad * 8]);
        #pragma unroll
        for (int nj = 0; nj < 2; nj++) {
            frag8 b = *reinterpret_cast<const frag8*>(&Bs[w * 32 + nj * 16 + lrow][quad * 8]);
            acc[nj] = __builtin_amdgcn_mfma_f32_16x16x32_bf16(a, b, acc[nj], 0, 0, 0);
        }
        __syncthreads();
    }

    float v[2][4];
    #pragma unroll
    for (int nj = 0; nj < 2; nj++) {
        int col = w * 32 + nj * 16 + lrow;
        #pragma unroll
        for (int r = 0; r < 4; r++) {
            int row = m0 + quad * 4 + r;
            float t = acc[nj][r];
            if (bias) t += bias[col];
            if (res) t += res[(size_t)row * 256 + col];
            v[nj][r] = t;
        }
    }

    if (g1) {
        #pragma unroll
        for (int r = 0; r < 4; r++) {
            float s1 = v[0][r] + v[1][r];
            float s2 = v[0][r]*v[0][r] + v[1][r]*v[1][r];
            s1 = row_sum16(s1); s2 = row_sum16(s2);
            if (lrow == 0) { red[w][quad * 4 + r][0] = s1; red[w][quad * 4 + r][1] = s2; }
        }
        __syncthreads();
        #pragma unroll
        for (int r = 0; r < 4; r++) {
            int rr = quad * 4 + r;
            float t1 = 0.f, t2 = 0.f;
            #pragma unroll
            for (int ww = 0; ww < 8; ww++) { t1 += red[ww][rr][0]; t2 += red[ww][rr][1]; }
            float mu = t1 * (1.0f / 256.0f);
            float var = t2 * (1.0f / 256.0f) - mu * mu;
            float rstd = rsqrtf(var + 1e-5f);
            #pragma unroll
            for (int nj = 0; nj < 2; nj++) {
                int col = w * 32 + nj * 16 + lrow;
                float t = (v[nj][r] - mu) * rstd * g1[col] + b1[col];
                if (gelu1) t = gelu_exact(t);
                v[nj][r] = t;
            }
        }
        __syncthreads();
    } else if (gelu1) {
        #pragma unroll
        for (int nj = 0; nj < 2; nj++)
            #pragma unroll
            for (int r = 0; r < 4; r++)
                v[nj][r] = gelu_exact(v[nj][r]);
    }

    if (outF) {
        #pragma unroll
        for (int nj = 0; nj < 2; nj++) {
            int col = w * 32 + nj * 16 + lrow;
            #pragma unroll
            for (int r = 0; r < 4; r++)
                outF[(size_t)(m0 + quad * 4 + r) * 256 + col] = v[nj][r];
        }
    }

    if (l2out) {
        #pragma unroll
        for (int r = 0; r < 4; r++) {
            float s2 = v[0][r]*v[0][r] + v[1][r]*v[1][r];
            s2 = row_sum16(s2);
            if (lrow == 0) red[w][quad * 4 + r][0] = s2;
        }
        __syncthreads();
        if (tid < 16) {
            float t = 0.f;
            #pragma unroll
            for (int ww = 0; ww < 8; ww++) t += red[ww][tid][0];
            sq[tid] = sqrtf(t);
        }
        __syncthreads();
        if (tid == 0) {
            float a = 0.f;
            #pragma unroll
            for (int i = 0; i < 16; i++) a += sq[i];
            atomicAdd(l2out, a * (0.01f / 4096.0f));
        }
    }

    if (g2) {
        __syncthreads();
        #pragma unroll
        for (int r = 0; r < 4; r++) {
            float s1 = v[0][r] + v[1][r];
            float s2 = v[0][r]*v[0][r] + v[1][r]*v[1][r];
            s1 = row_sum16(s1); s2 = row_sum16(s2);
            if (lrow == 0) { red[w][quad * 4 + r][0] = s1; red[w][quad * 4 + r][1] = s2; }
        }
        __syncthreads();
        #pragma unroll
        for (int r = 0; r < 4; r++) {
            int rr = quad * 4 + r;
            float t1 = 0.f, t2 = 0.f;
            #pragma unroll
            for (int ww = 0; ww < 8; ww++) { t1 += red[ww][rr][0]; t2 += red[ww][rr][1]; }
            float mu = t1 * (1.0f / 256.0f);
            float var = t2 * (1.0f / 256.0f) - mu * mu;
            float rstd = rsqrtf(var + 1e-5f);
            #pragma unroll
            for (int nj = 0; nj < 2; nj++) {
                int col = w * 32 + nj * 16 + lrow;
                outB[(size_t)(m0 + rr) * 256 + col] = bf16bits((v[nj][r] - mu) * rstd * g2[col] + b2[col]);
            }
        }
    } else if (outB) {
        #pragma unroll
        for (int nj = 0; nj < 2; nj++) {
            int col = w * 32 + nj * 16 + lrow;
            #pragma unroll
            for (int r = 0; r < 4; r++)
                outB[(size_t)(m0 + quad * 4 + r) * 256 + col] = bf16bits(v[nj][r]);
        }
    }

    // ---- fused cls GEMM: logits(16 x 128) = v(16 x 256) @ clsW(128 x 256)^T ----
    if (clsW) {
        #pragma unroll
        for (int nj = 0; nj < 2; nj++) {
            int col = w * 32 + nj * 16 + lrow;
            #pragma unroll
            for (int r = 0; r < 4; r++)
                hb[quad * 4 + r][col] = bf16bits(v[nj][r]);
        }
        __syncthreads();
        f32x4 cacc = {};
        #pragma unroll
        for (int k0 = 0; k0 < 256; k0 += 32) {
            frag8 a = *reinterpret_cast<const frag8*>(&hb[lrow][k0 + quad * 8]);
            frag8 b = *reinterpret_cast<const frag8*>(clsW + (size_t)(w * 16 + lrow) * 256 + k0 + quad * 8);
            cacc = __builtin_amdgcn_mfma_f32_16x16x32_bf16(a, b, cacc, 0, 0, 0);
        }
        int col = w * 16 + lrow;
        float cb = clsB[col];
        #pragma unroll
        for (int r = 0; r < 4; r++)
            clsOut[(size_t)(m0 + quad * 4 + r) * 128 + col] = cacc[r] + cb;
    }
}

// ---------------- dt proj + softplus -> dltT ; fused B/C transpose --------------
// xdbc partials: chunk 0 in xp0, chunks 1..3 in xp123 (stride S = 4096*48)
__global__ __launch_bounds__(256)
void dtbc(const float* __restrict__ xp0, const float* __restrict__ xp123,
          const float* __restrict__ dtw,
          const float* __restrict__ dtb, float* __restrict__ dltT,
          float* __restrict__ BT, float* __restrict__ CT)
{
    __shared__ float xd[64][17];
    __shared__ float wS[64][16];
    __shared__ float bS[64];
    const size_t S = (size_t)4096 * 48;
    const int bx = blockIdx.x;
    const int b = bx >> 7;
    const int tt = (bx >> 3) & 15;
    const int dg = bx & 7;
    const int tid = threadIdx.x;
    const int t0 = tt * 64, d0 = dg * 64;

    for (int i = tid; i < 64 * 16; i += 256) {
        int t = i >> 4, k = i & 15;
        size_t off = ((size_t)(b * 1024 + t0 + t)) * 48 + k;
        xd[t][k] = xp0[off] + xp123[off] + xp123[S + off] + xp123[2 * S + off];
    }
    for (int i = tid; i < 64 * 16; i += 256) {
        int dl = i >> 4, k = i & 15;
        wS[dl][k] = dtw[(d0 + dl) * 16 + k];
    }
    if (tid < 64) bS[tid] = dtb[d0 + tid];
    __syncthreads();

    const int tl = tid & 63, w = tid >> 6;
    #pragma unroll 4
    for (int di = 0; di < 16; di++) {
        int dl = w * 16 + di;
        float acc = bS[dl];
        #pragma unroll
        for (int k = 0; k < 16; k++) acc += xd[tl][k] * wS[dl][k];
        dltT[((size_t)(b * 512 + d0 + dl)) * 1024 + t0 + tl] = softplus_f(acc);
    }

    {
        int c = tid >> 6;
        int t = tid & 63;
        int col = dg * 4 + c;
        size_t off = ((size_t)(b * 1024 + t0 + t)) * 48 + 16 + col;
        float v = xp0[off] + xp123[off] + xp123[S + off] + xp123[2 * S + off];
        if (col < 16) BT[((size_t)(b * 16 + col)) * 1024 + t0 + t] = v;
        else          CT[((size_t)(b * 16 + col - 16)) * 1024 + t0 + t] = v;
    }
}

// ---------------- chunked selective scan (1 barrier, decentralized combine) -----
__global__ __launch_bounds__(1024)
void scan_chunked(const float* __restrict__ dltT, const float* __restrict__ ucT,
                  const float* __restrict__ BT, const float* __restrict__ CT,
                  const unsigned short* __restrict__ szT,
                  const float* __restrict__ Ac,
                  const float* __restrict__ Dp,
                  unsigned short* __restrict__ y)
{
    __shared__ float aprod_s[16][64];
    __shared__ float sfin_s[16][64];
    __shared__ float sin_w[16][64];
    __shared__ __align__(16) float ylocal[16][64][4];

    const int j = blockIdx.x;
    const int bid = (j & 7) * 64 + (j >> 3);     // XCD swizzle
    const int b = bid >> 7;
    const int d0 = (bid & 127) * 4;
    const int w = threadIdx.x >> 6;
    const int lane = threadIdx.x & 63;
    const int dsub = lane >> 4, s = lane & 15;
    const int d = d0 + dsub;

    const float Acoef = Ac[d * 16 + s];

    const float4* dp = reinterpret_cast<const float4*>(dltT + ((size_t)(b * 512 + d)) * 1024 + w * 64);
    const float4* up = reinterpret_cast<const float4*>(ucT  + ((size_t)(b * 512 + d)) * 1024 + w * 64);
    const float4* Bp = reinterpret_cast<const float4*>(BT + ((size_t)(b * 16 + s)) * 1024 + w * 64);
    const float4* Cp = reinterpret_cast<const float4*>(CT + ((size_t)(b * 16 + s)) * 1024 + w * 64);

    // ---- Phase A: local scan with cumprod (q+1 prefetch) ----
    float st = 0.0f, ap = 1.0f;
    float4 dt4 = dp[0], ut4 = up[0], B4 = Bp[0], C4 = Cp[0];
    #pragma unroll
    for (int q = 0; q < 16; q++) {
        float4 ndt, nut, nB, nC;
        if (q < 15) { ndt = dp[q + 1]; nut = up[q + 1]; nB = Bp[q + 1]; nC = Cp[q + 1]; }
        const float* dtp = (const float*)&dt4;
        const float* utp = (const float*)&ut4;
        const float* Btp = (const float*)&B4;
        const float* Ctp = (const float*)&C4;
        #pragma unroll
        for (int jj = 0; jj < 4; jj++) {
            float dA = __expf(dtp[jj] * Acoef);
            st = st * dA + dtp[jj] * utp[jj] * Btp[jj];
            ap *= dA;
            float part = row_sum16(st * Ctp[jj]);
            if (s == 0) ylocal[w][q * 4 + jj][dsub] = part;
        }
        dt4 = ndt; ut4 = nut; B4 = nB; C4 = nC;
    }
    aprod_s[w][lane] = ap;
    sfin_s[w][lane] = st;
    __syncthreads();                                 // the only barrier

    // ---- decentralized combine ----
    {
        float pre = 0.0f;
        #pragma unroll
        for (int c = 0; c < 15; c++) {
            float apc = aprod_s[c][lane];
            float sfc = sfin_s[c][lane];
            float cand = sfc + apc * pre;
            pre = (c < w) ? cand : pre;
        }
        sin_w[w][lane] = pre;
    }

    // ---- Phase C: lane = t; correction via prefix sums + epilogue ----
    const int t = w * 64 + lane;
    float cums[4];
    #pragma unroll
    for (int dd = 0; dd < 4; dd++)
        cums[dd] = dltT[((size_t)(b * 512 + d0 + dd)) * 1024 + t];
    #pragma unroll
    for (int dd = 0; dd < 4; dd++)
        cums[dd] = prefix_sum64(cums[dd]);

    float4 yl = *reinterpret_cast<const float4*>(&ylocal[w][lane][0]);
    float acc[4] = { yl.x, yl.y, yl.z, yl.w };

    #pragma unroll
    for (int sq = 0; sq < 4; sq++) {
        float Cs[4];
        #pragma unroll
        for (int jj = 0; jj < 4; jj++)
            Cs[jj] = CT[((size_t)(b * 16 + sq * 4 + jj)) * 1024 + t];
        #pragma unroll
        for (int dd = 0; dd < 4; dd++) {
            float4 sin4 = *reinterpret_cast<const float4*>(&sin_w[w][dd * 16 + sq * 4]);
            const float* sp = (const float*)&sin4;
            #pragma unroll
            for (int jj = 0; jj < 4; jj++) {
                float ac = Ac[(d0 + dd) * 16 + sq * 4 + jj];
                acc[dd] += sp[jj] * Cs[jj] * __expf(ac * cums[dd]);
            }
        }
    }

    const size_t row = (size_t)b * 1024 + t;
    #pragma unroll
    for (int dd = 0; dd < 4; dd++) {
        float ut = ucT[((size_t)(b * 512 + d0 + dd)) * 1024 + t];
        float sz = bf2f(szT[((size_t)(b * 512 + d0 + dd)) * 1024 + t]);
        float yv = acc[dd] + ut * Dp[d0 + dd];
        y[row * 512 + d0 + dd] = bf16bits(yv * sz);
    }
}

// ---------------- launcher ----------------
extern "C" void kernel_launch(void* const* d_in, const int* in_sizes, int n_in,
                              void* d_out, int out_size, void* d_ws, size_t ws_size,
                              hipStream_t stream)
{
    const float* x      = (const float*)d_in[0];
    const float* in_b   = (const float*)d_in[2];
    const float* ln_g   = (const float*)d_in[3];
    const float* ln_b   = (const float*)d_in[4];
    const float* blk_ng  = (const float*)d_in[5];
    const float* blk_nb  = (const float*)d_in[6];
    const float* blk_cw  = (const float*)d_in[8];
    const float* blk_cb  = (const float*)d_in[9];
    const float* blk_dtw = (const float*)d_in[11];
    const float* blk_dtb = (const float*)d_in[12];
    const float* blk_Alog= (const float*)d_in[13];
    const float* blk_D   = (const float*)d_in[14];
    const float* op_b   = (const float*)d_in[17];
    const float* cls_b  = (const float*)d_in[19];
    float* out = (float*)d_out;

    const int BL = 4096;
    float* ws = (float*)d_ws;
    float* h0   = ws;                         // 1,048,576
    float* xzuT = h0 + 1048576;               // 2,097,152  [b][d][t] fp32 (u pre-conv)
    float* ucT  = xzuT + 2097152;             // 2,097,152  [b][d][t]
    float* xdbc = ucT + 2097152;              //   196,608  (xdbcp chunk 0)
    float* dltT = xdbc + 196608;              // 2,097,152  [b][d][t]
    float* BT   = dltT + 2097152;             //    65,536  [b][s][t]
    float* CT   = BT + 65536;                 //    65,536  [b][s][t]
    float* Ac   = CT + 65536;                 //    16,384
    unsigned short* szT = (unsigned short*)(Ac + 16384);  // 2,097,152 bf16 [b][d][t]
    unsigned short* wb  = szT + 2097152;      // 1,130,496
    unsigned short* hnb = wb + 1130496;       // 1,048,576
    unsigned short* ybb = hnb + 1048576;      // 2,097,152
    unsigned short* xb  = (unsigned short*)dltT;  // x bf16 (dead before dltT written)
    unsigned short* h0b = hnb;
    float* xp123 = (float*)ybb;               // xdbcp chunks 1..3 (dead-ybb alias,
                                              // 3*196,608 floats < ybb's 4 MB)
    unsigned short* in_wb  = wb;
    unsigned short* ipw_b  = wb + 196608;
    unsigned short* xpw_b  = wb + 720896;
    unsigned short* opw_b  = wb + 770048;
    unsigned short* op_wb  = wb + 1032192;
    unsigned short* cls_wb = wb + 1097728;

    CvtArgs ca;
    ca.src[0] = x;                  ca.dst[0] = xb;     ca.n4[0] = 3145728 / 4;
    ca.src[1] = (const float*)d_in[1];  ca.dst[1] = in_wb;  ca.n4[1] = 196608 / 4;
    ca.src[2] = (const float*)d_in[7];  ca.dst[2] = ipw_b;  ca.n4[2] = 524288 / 4;
    ca.src[3] = (const float*)d_in[10]; ca.dst[3] = xpw_b;  ca.n4[3] = 49152 / 4;
    ca.src[4] = (const float*)d_in[15]; ca.dst[4] = opw_b;  ca.n4[4] = 262144 / 4;
    ca.src[5] = (const float*)d_in[16]; ca.dst[5] = op_wb;  ca.n4[5] = 65536 / 4;
    ca.src[6] = (const float*)d_in[18]; ca.dst[6] = cls_wb; ca.n4[6] = 32768 / 4;
    int total4 = (3145728 + 1130496) / 4;
    int totalg = total4 + 16384;
    cvt_all<<<(totalg + 255) / 256, 256, 0, stream>>>(ca, total4, blk_Alog, Ac,
                                                      out + (size_t)BL * 128);

    // in_proj + bias + LN + GELU -> h0 (fp32), + LN(layer0) -> hnb (bf16)
    rowgemm<<<256, 512, 0, stream>>>(xb, in_wb, in_b, nullptr,
                                     ln_g, ln_b, 1,
                                     blk_ng, blk_nb,
                                     h0, hnb, nullptr,
                                     nullptr, nullptr, nullptr, 768);

    for (int l = 0; l < 2; l++) {
        const float* cw   = blk_cw  + (size_t)l * 512 * 4;
        const float* cb   = blk_cb  + l * 512;
        const float* dtw  = blk_dtw + (size_t)l * 512 * 16;
        const float* dtb  = blk_dtb + l * 512;
        const float* Dl   = blk_D   + l * 512;
        const unsigned short* ipwl = ipw_b + (size_t)l * 262144;
        const unsigned short* xpwl = xpw_b + (size_t)l * 24576;
        const unsigned short* opwl = opw_b + (size_t)l * 131072;

        // ipw GEMM: u -> xzuT fp32 [b][d][t]; z -> silu(z) bf16 szT [b][d][t]
        gemm_ipw<<<dim3(16, 64), 256, 0, stream>>>(hnb, ipwl, xzuT, szT);
        // fused conv + xpw projection (K-split x4): writes ucT + xdbc partials
        gemm_cat<<<dim3(4, 64), 256, 0, stream>>>(xzuT, xpwl, cw, cb, ucT, xdbc, xp123);
        // dltT (softplus, sums partials) + fused BT/CT transpose
        dtbc<<<512, 256, 0, stream>>>(xdbc, xp123, dtw, dtb, dltT, BT, CT);
        // scan -> ybb
        scan_chunked<<<512, 1024, 0, stream>>>(dltT, ucT, BT, CT, szT,
                                               Ac + (size_t)l * 8192, Dl, ybb);
        // h0 += ybb @ opw.T; layer0: +LN(layer1)->hnb; layer1: ->h0b bf16 only
        if (l == 0)
            rowgemm<<<256, 512, 0, stream>>>(ybb, opwl, nullptr, h0,
                                             nullptr, nullptr, 0,
                                             blk_ng + 256, blk_nb + 256,
                                             h0, hnb, nullptr,
                                             nullptr, nullptr, nullptr, 512);
        else
            rowgemm<<<256, 512, 0, stream>>>(ybb, opwl, nullptr, h0,
                                             nullptr, nullptr, 0,
                                             nullptr, nullptr,
                                             nullptr, h0b, nullptr,
                                             nullptr, nullptr, nullptr, 512);
    }

    // final: h2 = gelu(h0b @ op_w.T + op_b); fused L2 scalar + cls GEMM -> out
    rowgemm<<<256, 512, 0, stream>>>(h0b, op_wb, op_b, nullptr,
                                     nullptr, nullptr, 1,
                                     nullptr, nullptr,
                                     nullptr, nullptr, out + (size_t)BL * 128,
                                     cls_wb, cls_b, out, 256);
}